// Round 8
// baseline (216.045 us; speedup 1.0000x reference)
//
#include <hip/hip_runtime.h>
#include <hip/hip_bf16.h>

#define BB 2
#define TT 2048
#define DMM 1024
#define HH 16
#define HDD 64

typedef __attribute__((ext_vector_type(8))) short bf16x8;
typedef __attribute__((ext_vector_type(4))) short short4v;
typedef __attribute__((ext_vector_type(4))) float f32x4;

static __device__ __forceinline__ short f2bf(float f) {
    __hip_bfloat16 h = __float2bfloat16(f);
    return *reinterpret_cast<short*>(&h);
}

// ---- hidden f32 -> bf16 (4 elems/thread) ----
__global__ void cvt_hidden(const float* __restrict__ x, short* __restrict__ y) {
    int i = blockIdx.x * 256 + threadIdx.x;          // 1M threads, 4M elems
    float4 v = reinterpret_cast<const float4*>(x)[i];
    short4v o;
    o[0] = f2bf(v.x); o[1] = f2bf(v.y); o[2] = f2bf(v.z); o[3] = f2bf(v.w);
    reinterpret_cast<short4v*>(y)[i] = o;
}

// ---- W_eff = W + 2.0 * B@A  (or plain W), cast bf16 ----
__global__ void prep_w(const float* __restrict__ W, const float* __restrict__ A,
                       const float* __restrict__ Bm, short* __restrict__ outp, int lora) {
    int idx = blockIdx.x * 256 + threadIdx.x;        // 1M elems
    int n = idx >> 10, k = idx & 1023;
    float v = W[idx];
    if (lora) {
        float s = 0.f;
#pragma unroll
        for (int r = 0; r < 8; ++r) s += Bm[n * 8 + r] * A[r * 1024 + k];
        v += 2.0f * s;
    }
    outp[idx] = f2bf(v);
}

// ---- projection GEMM: C[m,n] = X[m,:] . W[n,:]  (both row-major, K contiguous) ----
// z = 0: Q (scale 0.125, layout [b][h][t][d]); z=1: K (same layout); z=2: V -> [b][h][d][t]
__global__ __launch_bounds__(256) void proj_gemm(
        const short* __restrict__ Xbf,
        const short* __restrict__ Wq, const short* __restrict__ Wk, const short* __restrict__ Wv,
        const float* __restrict__ bq, const float* __restrict__ bk, const float* __restrict__ bv,
        short* __restrict__ Qb, short* __restrict__ Kb, short* __restrict__ Vtb) {
    __shared__ __align__(16) char As[128 * 128];     // 128 rows x 64 bf16 (128B), swizzled
    __shared__ __align__(16) char Bs[128 * 128];

    const int mode = blockIdx.z;
    const short* Wbf = (mode == 0) ? Wq : (mode == 1) ? Wk : Wv;
    const float* bias = (mode == 0) ? bq : (mode == 1) ? bk : bv;
    short* outp = (mode == 0) ? Qb : (mode == 1) ? Kb : Vtb;
    const float scale = (mode == 0) ? 0.125f : 1.0f;  // HD^-0.5 folded into Q

    const int tid = threadIdx.x;
    const int wave = tid >> 6, lane = tid & 63;
    const int l15 = lane & 15, l4 = lane >> 4;
    const int m0 = blockIdx.y * 128, n0 = blockIdx.x * 128;
    const int wm = (wave >> 1) * 64, wn = (wave & 1) * 64;

    const int srow = tid >> 1;            // staging row 0..127
    const int scc = (tid & 1) * 4;        // 16B-chunk base (of 8 per row)

    f32x4 acc[4][4] = {};

    for (int k0 = 0; k0 < 1024; k0 += 64) {
        __syncthreads();
#pragma unroll
        for (int c = 0; c < 4; ++c) {
            int cc = scc + c;
            uint4 va = *reinterpret_cast<const uint4*>(Xbf + (m0 + srow) * 1024 + k0 + cc * 8);
            *reinterpret_cast<uint4*>(As + ((srow * 128 + cc * 16) ^ ((srow & 7) << 4))) = va;
            uint4 vb = *reinterpret_cast<const uint4*>(Wbf + (n0 + srow) * 1024 + k0 + cc * 8);
            *reinterpret_cast<uint4*>(Bs + ((srow * 128 + cc * 16) ^ ((srow & 7) << 4))) = vb;
        }
        __syncthreads();
#pragma unroll
        for (int kk = 0; kk < 2; ++kk) {
            const int colb = kk * 64 + l4 * 16;
            bf16x8 af[4], bfr[4];
#pragma unroll
            for (int mi = 0; mi < 4; ++mi) {
                int rowa = wm + mi * 16 + l15;
                af[mi] = *reinterpret_cast<const bf16x8*>(As + ((rowa * 128 + colb) ^ ((rowa & 7) << 4)));
                int rowb = wn + mi * 16 + l15;
                bfr[mi] = *reinterpret_cast<const bf16x8*>(Bs + ((rowb * 128 + colb) ^ ((rowb & 7) << 4)));
            }
#pragma unroll
            for (int mi = 0; mi < 4; ++mi)
#pragma unroll
                for (int ni = 0; ni < 4; ++ni)
                    acc[mi][ni] = __builtin_amdgcn_mfma_f32_16x16x32_bf16(af[mi], bfr[ni], acc[mi][ni], 0, 0, 0);
        }
    }

    // epilogue: C row = (l>>4)*4 + r, col = l&15
#pragma unroll
    for (int mi = 0; mi < 4; ++mi)
#pragma unroll
        for (int ni = 0; ni < 4; ++ni) {
            int gn = n0 + wn + ni * 16 + l15;
            float bv = bias[gn];
            int h = gn >> 6, d = gn & 63;
#pragma unroll
            for (int r = 0; r < 4; ++r) {
                int gm = m0 + wm + mi * 16 + l4 * 4 + r;
                int b = gm >> 11, t = gm & 2047;
                float v = (acc[mi][ni][r] + bv) * scale;
                int off;
                if (mode == 2) off = ((b * 16 + h) * 64 + d) * 2048 + t;     // V transposed
                else           off = ((b * 16 + h) * 2048 + t) * 64 + d;
                outp[off] = f2bf(v);
            }
        }
}

// ---- flash attention v6: swapped-QK + split-KV, 4 waves/SIMD ----
// 1024 blocks x 4 waves = 4096 waves. Block = 2 pairs; wave (pg, hf):
//   hf=0: A-tiles [0,hA)   then B-tiles [hB,nktB)   (A-early + B-late)
//   hf=1: A-tiles [hA,nktA) then B-tiles [0,hB)     (A-late + B-early)
// ~uniform (~33 tile-units/wave). Phase-1 partial (O^T,m,l) posted to LDS
// before phase 2 (frees regs); one barrier; h0 merges A, h1 merges B.
// Steady-state loop has ZERO cross-lane ops: defer-max via lane-local max
// (__all check), per-lane partial l reduced once per phase.

#define LOADK32(dst, kvb_) do {                                                      \
    int _kb = (kvb_);                                                                \
    _Pragma("unroll")                                                                \
    for (int _sl = 0; _sl < 2; ++_sl) {                                              \
        dst[_sl][0] = *reinterpret_cast<const bf16x8*>(Kp + (_kb + _sl*16 + l15)*64 + l4*8);      \
        dst[_sl][1] = *reinterpret_cast<const bf16x8*>(Kp + (_kb + _sl*16 + l15)*64 + 32 + l4*8); \
    }                                                                                \
} while (0)

#define STEP1(CUR, NXT, KT, QBASE, QF0, QF1, OO, M, L) do {                          \
    bf16x8 (*cur)[2] = CUR;                                                          \
    const int kvb = (KT) << 5;                                                       \
    LOADK32(NXT, kvb + 32);                                                          \
    bf16x8 vf[4];                                                                    \
    _Pragma("unroll")                                                                \
    for (int dt = 0; dt < 4; ++dt)                                                   \
        vf[dt] = *reinterpret_cast<const bf16x8*>(Vp + (dt*16 + l15)*2048 + kvb + l4*8); \
    float4 mv0 = *reinterpret_cast<const float4*>(mp + kvb + l4*4);                  \
    float4 mv1 = *reinterpret_cast<const float4*>(mp + kvb + 16 + l4*4);             \
    f32x4 s0 = {}, s1 = {};                                                          \
    s0 = __builtin_amdgcn_mfma_f32_16x16x32_bf16(cur[0][0], QF0, s0, 0, 0, 0);       \
    s0 = __builtin_amdgcn_mfma_f32_16x16x32_bf16(cur[0][1], QF1, s0, 0, 0, 0);       \
    s1 = __builtin_amdgcn_mfma_f32_16x16x32_bf16(cur[1][0], QF0, s1, 0, 0, 0);       \
    s1 = __builtin_amdgcn_mfma_f32_16x16x32_bf16(cur[1][1], QF1, s1, 0, 0, 0);       \
    float pr0[4], pr1[4];                                                            \
    if (kvb + 31 > (QBASE)) {                                                        \
        _Pragma("unroll")                                                            \
        for (int r = 0; r < 4; ++r) {                                                \
            float v0 = s0[r] + mv0[r];                                               \
            if (kvb + l4*4 + r > (QBASE) + l15) v0 = -1e30f;                         \
            pr0[r] = v0;                                                             \
            float v1 = s1[r] + mv1[r];                                               \
            if (kvb + 16 + l4*4 + r > (QBASE) + l15) v1 = -1e30f;                    \
            pr1[r] = v1;                                                             \
        }                                                                            \
    } else {                                                                         \
        _Pragma("unroll")                                                            \
        for (int r = 0; r < 4; ++r) { pr0[r] = s0[r] + mv0[r]; pr1[r] = s1[r] + mv1[r]; } \
    }                                                                                \
    float tl = fmaxf(fmaxf(fmaxf(pr0[0], pr0[1]), fmaxf(pr0[2], pr0[3])),            \
                     fmaxf(fmaxf(pr1[0], pr1[1]), fmaxf(pr1[2], pr1[3])));           \
    if (!__all(tl - (M) <= 8.0f)) {                                                  \
        float tm = tl;                                                               \
        tm = fmaxf(tm, __shfl_xor(tm, 16));                                          \
        tm = fmaxf(tm, __shfl_xor(tm, 32));                                          \
        float mn = fmaxf((M), tm);                                                   \
        float al = __expf((M) - mn);                                                 \
        M = mn; L *= al;                                                             \
        _Pragma("unroll")                                                            \
        for (int dt = 0; dt < 4; ++dt)                                               \
            _Pragma("unroll")                                                        \
            for (int r = 0; r < 4; ++r) OO[dt][r] *= al;                             \
    }                                                                                \
    _Pragma("unroll")                                                                \
    for (int r = 0; r < 4; ++r) { pr0[r] = __expf(pr0[r] - (M)); pr1[r] = __expf(pr1[r] - (M)); } \
    L += (pr0[0] + pr0[1]) + (pr0[2] + pr0[3])                                       \
       + (pr1[0] + pr1[1]) + (pr1[2] + pr1[3]);                                      \
    short4v w0, w1;                                                                  \
    _Pragma("unroll")                                                                \
    for (int r = 0; r < 4; ++r) { w0[r] = f2bf(pr0[r]); w1[r] = f2bf(pr1[r]); }      \
    *reinterpret_cast<short4v*>(pbw + l15*40 + l4*4)      = w0;                      \
    *reinterpret_cast<short4v*>(pbw + l15*40 + 16 + l4*4) = w1;                      \
    asm volatile("s_waitcnt lgkmcnt(0)" ::: "memory");                               \
    bf16x8 pf = *reinterpret_cast<const bf16x8*>(pbw + l15*40 + l4*8);               \
    _Pragma("unroll")                                                                \
    for (int dt = 0; dt < 4; ++dt)                                                   \
        OO[dt] = __builtin_amdgcn_mfma_f32_16x16x32_bf16(vf[dt], pf, OO[dt], 0, 0, 0); \
} while (0)

#define PHASE(QBASE, KT0, KT1, QF0, QF1, OO, M, L) do {                              \
    int kt = (KT0);                                                                  \
    if (kt < (KT1)) {                                                                \
        bf16x8 kfP[2][2], kfQ[2][2];                                                 \
        LOADK32(kfP, kt << 5);                                                       \
        while (1) {                                                                  \
            STEP1(kfP, kfQ, kt, QBASE, QF0, QF1, OO, M, L);                          \
            if (++kt >= (KT1)) break;                                                \
            STEP1(kfQ, kfP, kt, QBASE, QF0, QF1, OO, M, L);                          \
            if (++kt >= (KT1)) break;                                                \
        }                                                                            \
    }                                                                                \
} while (0)

// LDS layout (bytes): pb: wv*1280 (4x1280=5120) | mrg1: 5120+wv*5120 (20480)
//                     | mrg2: 25600+pg*5120 (10240) -> total 35840
__global__ __launch_bounds__(256) void attn(
        const short* __restrict__ Qb, const short* __restrict__ Kb,
        const short* __restrict__ Vt, const float* __restrict__ amask,
        float* __restrict__ outp) {
    __shared__ __align__(16) char MEM[35840];

    const int tid = threadIdx.x, wv = tid >> 6, lane = tid & 63;
    const int l15 = lane & 15, l4 = lane >> 4;
    // XCD-chunked swizzle: 1024 blocks, HW id x -> work id (x%8)*128 + x/8
    const int wid = ((blockIdx.x & 7) << 7) + (blockIdx.x >> 3);
    const int bh = wid >> 5;                         // 32 (b,h)
    const int j  = wid & 31;
    const int pg = wv >> 1;                          // pair group in block
    const int hf = wv & 1;                           // half
    const int i  = 2 * j + pg;                       // pair index 0..63
    const int b = bh >> 4, h = bh & 15;

    const short* Qp = Qb + bh * TT * HDD;
    const short* Kp = Kb + bh * TT * HDD;
    const short* Vp = Vt + bh * HDD * TT;
    const float* mp = amask + b * TT;
    short* pbw = (short*)(MEM + wv * 1280);

    const int qbaseA = (127 - i) << 4;
    const int qbaseB = i << 4;
    const int nktA = (qbaseA + 47) >> 5;             // >= 33
    const int nktB = (qbaseB + 47) >> 5;             // >= 1
    const int hA = (nktA + 1) >> 1;
    const int hB = (nktB + 1) >> 1;

    // ---- phase 1: tile A portion ----
    {
        bf16x8 qf0 = *reinterpret_cast<const bf16x8*>(Qp + (qbaseA + l15) * 64 + l4 * 8);
        bf16x8 qf1 = *reinterpret_cast<const bf16x8*>(Qp + (qbaseA + l15) * 64 + 32 + l4 * 8);
        f32x4 O[4] = {};
        float M = -1e30f, L = 0.f;
        const int kt0 = hf ? hA : 0;
        const int kt1 = hf ? nktA : hA;
        PHASE(qbaseA, kt0, kt1, qf0, qf1, O, M, L);
        float Lt = L;
        Lt += __shfl_xor(Lt, 16);
        Lt += __shfl_xor(Lt, 32);
        float* mg = (float*)(MEM + 5120 + wv * 5120) + lane * 20;
#pragma unroll
        for (int dt = 0; dt < 4; ++dt)
            *reinterpret_cast<f32x4*>(mg + dt * 4) = O[dt];
        mg[16] = M; mg[17] = Lt;
    }

    // ---- phase 2: tile B portion (partial state stays in regs) ----
    f32x4 OB[4] = {};
    float MB = -1e30f, LB = 0.f;
    {
        bf16x8 qf0 = *reinterpret_cast<const bf16x8*>(Qp + (qbaseB + l15) * 64 + l4 * 8);
        bf16x8 qf1 = *reinterpret_cast<const bf16x8*>(Qp + (qbaseB + l15) * 64 + 32 + l4 * 8);
        const int kt0 = hf ? 0 : hB;
        const int kt1 = hf ? hB : nktB;
        PHASE(qbaseB, kt0, kt1, qf0, qf1, OB, MB, LB);
        float Lt = LB;
        Lt += __shfl_xor(Lt, 16);
        Lt += __shfl_xor(Lt, 32);
        LB = Lt;
        if (!hf) {                                   // h0 posts B-late for h1
            float* mg = (float*)(MEM + 25600 + pg * 5120) + lane * 20;
#pragma unroll
            for (int dt = 0; dt < 4; ++dt)
                *reinterpret_cast<f32x4*>(mg + dt * 4) = OB[dt];
            mg[16] = MB; mg[17] = LB;
        }
    }

    __syncthreads();

    if (!hf) {
        // merge tile A from the two posted halves; write out
        const float* g0 = (const float*)(MEM + 5120 + (pg * 2 + 0) * 5120) + lane * 20;
        const float* g1 = (const float*)(MEM + 5120 + (pg * 2 + 1) * 5120) + lane * 20;
        float m0 = g0[16], l0 = g0[17];
        float m1 = g1[16], l1 = g1[17];
        float ms = fmaxf(m0, m1);
        float e0 = __expf(m0 - ms), e1 = __expf(m1 - ms);
        float inv = 1.0f / (l0 * e0 + l1 * e1);
        int t = qbaseA + l15;
#pragma unroll
        for (int dt = 0; dt < 4; ++dt) {
            f32x4 o0 = *reinterpret_cast<const f32x4*>(g0 + dt * 4);
            f32x4 o1 = *reinterpret_cast<const f32x4*>(g1 + dt * 4);
            float4 o;
            o.x = (o0[0] * e0 + o1[0] * e1) * inv;
            o.y = (o0[1] * e0 + o1[1] * e1) * inv;
            o.z = (o0[2] * e0 + o1[2] * e1) * inv;
            o.w = (o0[3] * e0 + o1[3] * e1) * inv;
            *reinterpret_cast<float4*>(outp + (b * 2048 + t) * 1024 + h * 64 + dt * 16 + l4 * 4) = o;
        }
    } else {
        // merge tile B: own B-early (regs) + partner's B-late (LDS); write out
        const float* g1 = (const float*)(MEM + 25600 + pg * 5120) + lane * 20;
        float m1 = g1[16], l1 = g1[17];
        float ms = fmaxf(MB, m1);
        float e0 = __expf(MB - ms), e1 = __expf(m1 - ms);
        float inv = 1.0f / (LB * e0 + l1 * e1);
        int t = qbaseB + l15;
#pragma unroll
        for (int dt = 0; dt < 4; ++dt) {
            f32x4 o1 = *reinterpret_cast<const f32x4*>(g1 + dt * 4);
            float4 o;
            o.x = (OB[dt][0] * e0 + o1[0] * e1) * inv;
            o.y = (OB[dt][1] * e0 + o1[1] * e1) * inv;
            o.z = (OB[dt][2] * e0 + o1[2] * e1) * inv;
            o.w = (OB[dt][3] * e0 + o1[3] * e1) * inv;
            *reinterpret_cast<float4*>(outp + (b * 2048 + t) * 1024 + h * 64 + dt * 16 + l4 * 4) = o;
        }
    }
}

extern "C" void kernel_launch(void* const* d_in, const int* in_sizes, int n_in,
                              void* d_out, int out_size, void* d_ws, size_t ws_size,
                              hipStream_t stream) {
    const float* hidden = (const float*)d_in[0];
    const float* amask  = (const float*)d_in[1];
    const float* Wq = (const float*)d_in[2];
    const float* bq = (const float*)d_in[3];
    const float* Aq = (const float*)d_in[4];
    const float* Bq = (const float*)d_in[5];
    const float* Wk = (const float*)d_in[6];
    const float* bk = (const float*)d_in[7];
    const float* Wv = (const float*)d_in[8];
    const float* bv = (const float*)d_in[9];
    const float* Av = (const float*)d_in[10];
    const float* Bv = (const float*)d_in[11];
    float* outp = (float*)d_out;

    char* ws = (char*)d_ws;
    short* Xbf = (short*)(ws);                 // 8 MB  [4096][1024] bf16
    short* Wqe = (short*)(ws + (8 << 20));     // 2 MB
    short* Wke = (short*)(ws + (10 << 20));    // 2 MB
    short* Wve = (short*)(ws + (12 << 20));    // 2 MB
    short* Qb  = (short*)(ws + (14 << 20));    // 8 MB  [b][h][t][d]
    short* Kb  = (short*)(ws + (22 << 20));    // 8 MB  [b][h][t][d]
    short* Vtb = (short*)(ws + (30 << 20));    // 8 MB  [b][h][d][t]

    cvt_hidden<<<4096, 256, 0, stream>>>(hidden, Xbf);
    prep_w<<<4096, 256, 0, stream>>>(Wq, Aq, Bq, Wqe, 1);
    prep_w<<<4096, 256, 0, stream>>>(Wk, nullptr, nullptr, Wke, 0);
    prep_w<<<4096, 256, 0, stream>>>(Wv, Av, Bv, Wve, 1);
    proj_gemm<<<dim3(8, 32, 3), 256, 0, stream>>>(Xbf, Wqe, Wke, Wve, bq, bk, bv, Qb, Kb, Vtb);
    attn<<<1024, 256, 0, stream>>>(Qb, Kb, Vtb, amask, outp);
}

// Round 9
// 142.203 us; speedup vs baseline: 1.5193x; 1.5193x over previous
//
#include <hip/hip_runtime.h>
#include <hip/hip_bf16.h>

#define BB 2
#define TT 2048
#define DMM 1024
#define HH 16
#define HDD 64

typedef __attribute__((ext_vector_type(8))) short bf16x8;
typedef __attribute__((ext_vector_type(4))) short short4v;
typedef __attribute__((ext_vector_type(4))) float f32x4;

static __device__ __forceinline__ short f2bf(float f) {
    __hip_bfloat16 h = __float2bfloat16(f);
    return *reinterpret_cast<short*>(&h);
}

static __device__ __forceinline__ void gl_lds16(const void* g, void* l) {
    __builtin_amdgcn_global_load_lds(
        (const __attribute__((address_space(1))) void*)g,
        (__attribute__((address_space(3))) void*)l, 16, 0, 0);
}

// ---- hidden f32 -> bf16 (4 elems/thread) ----
__global__ void cvt_hidden(const float* __restrict__ x, short* __restrict__ y) {
    int i = blockIdx.x * 256 + threadIdx.x;          // 1M threads, 4M elems
    float4 v = reinterpret_cast<const float4*>(x)[i];
    short4v o;
    o[0] = f2bf(v.x); o[1] = f2bf(v.y); o[2] = f2bf(v.z); o[3] = f2bf(v.w);
    reinterpret_cast<short4v*>(y)[i] = o;
}

// ---- W_eff = W + 2.0 * B@A  (or plain W), cast bf16 ----
__global__ void prep_w(const float* __restrict__ W, const float* __restrict__ A,
                       const float* __restrict__ Bm, short* __restrict__ outp, int lora) {
    int idx = blockIdx.x * 256 + threadIdx.x;        // 1M elems
    int n = idx >> 10, k = idx & 1023;
    float v = W[idx];
    if (lora) {
        float s = 0.f;
#pragma unroll
        for (int r = 0; r < 8; ++r) s += Bm[n * 8 + r] * A[r * 1024 + k];
        v += 2.0f * s;
    }
    outp[idx] = f2bf(v);
}

// ---- projection GEMM: C[m,n] = X[m,:] . W[n,:]  (both row-major, K contiguous) ----
// z = 0: Q (scale 0.125, layout [b][h][t][d]); z=1: K (same layout); z=2: V -> [b][h][d][t]
__global__ __launch_bounds__(256) void proj_gemm(
        const short* __restrict__ Xbf,
        const short* __restrict__ Wq, const short* __restrict__ Wk, const short* __restrict__ Wv,
        const float* __restrict__ bq, const float* __restrict__ bk, const float* __restrict__ bv,
        short* __restrict__ Qb, short* __restrict__ Kb, short* __restrict__ Vtb) {
    __shared__ __align__(16) char As[128 * 128];     // 128 rows x 64 bf16 (128B), swizzled
    __shared__ __align__(16) char Bs[128 * 128];

    const int mode = blockIdx.z;
    const short* Wbf = (mode == 0) ? Wq : (mode == 1) ? Wk : Wv;
    const float* bias = (mode == 0) ? bq : (mode == 1) ? bk : bv;
    short* outp = (mode == 0) ? Qb : (mode == 1) ? Kb : Vtb;
    const float scale = (mode == 0) ? 0.125f : 1.0f;  // HD^-0.5 folded into Q

    const int tid = threadIdx.x;
    const int wave = tid >> 6, lane = tid & 63;
    const int l15 = lane & 15, l4 = lane >> 4;
    const int m0 = blockIdx.y * 128, n0 = blockIdx.x * 128;
    const int wm = (wave >> 1) * 64, wn = (wave & 1) * 64;

    const int srow = tid >> 1;            // staging row 0..127
    const int scc = (tid & 1) * 4;        // 16B-chunk base (of 8 per row)

    f32x4 acc[4][4] = {};

    for (int k0 = 0; k0 < 1024; k0 += 64) {
        __syncthreads();
#pragma unroll
        for (int c = 0; c < 4; ++c) {
            int cc = scc + c;
            uint4 va = *reinterpret_cast<const uint4*>(Xbf + (m0 + srow) * 1024 + k0 + cc * 8);
            *reinterpret_cast<uint4*>(As + ((srow * 128 + cc * 16) ^ ((srow & 7) << 4))) = va;
            uint4 vb = *reinterpret_cast<const uint4*>(Wbf + (n0 + srow) * 1024 + k0 + cc * 8);
            *reinterpret_cast<uint4*>(Bs + ((srow * 128 + cc * 16) ^ ((srow & 7) << 4))) = vb;
        }
        __syncthreads();
#pragma unroll
        for (int kk = 0; kk < 2; ++kk) {
            const int colb = kk * 64 + l4 * 16;
            bf16x8 af[4], bfr[4];
#pragma unroll
            for (int mi = 0; mi < 4; ++mi) {
                int rowa = wm + mi * 16 + l15;
                af[mi] = *reinterpret_cast<const bf16x8*>(As + ((rowa * 128 + colb) ^ ((rowa & 7) << 4)));
                int rowb = wn + mi * 16 + l15;
                bfr[mi] = *reinterpret_cast<const bf16x8*>(Bs + ((rowb * 128 + colb) ^ ((rowb & 7) << 4)));
            }
#pragma unroll
            for (int mi = 0; mi < 4; ++mi)
#pragma unroll
                for (int ni = 0; ni < 4; ++ni)
                    acc[mi][ni] = __builtin_amdgcn_mfma_f32_16x16x32_bf16(af[mi], bfr[ni], acc[mi][ni], 0, 0, 0);
        }
    }

    // epilogue: C row = (l>>4)*4 + r, col = l&15
#pragma unroll
    for (int mi = 0; mi < 4; ++mi)
#pragma unroll
        for (int ni = 0; ni < 4; ++ni) {
            int gn = n0 + wn + ni * 16 + l15;
            float bv = bias[gn];
            int h = gn >> 6, d = gn & 63;
#pragma unroll
            for (int r = 0; r < 4; ++r) {
                int gm = m0 + wm + mi * 16 + l4 * 4 + r;
                int b = gm >> 11, t = gm & 2047;
                float v = (acc[mi][ni][r] + bv) * scale;
                int off;
                if (mode == 2) off = ((b * 16 + h) * 64 + d) * 2048 + t;     // V transposed
                else           off = ((b * 16 + h) * 2048 + t) * 64 + d;
                outp[off] = f2bf(v);
            }
        }
}

// ---- flash attention v7: block-shared LDS K/V staging (global_load_lds), swapped-QK ----
// 512 blocks x 4 waves; block = one (b,h) + 4 pairs i = 4j+wv (A=127-i big, B=i small).
// KV stream staged ONCE per block: KVBLK=32, K tile 4KB + V^T tile 4KB, double-buffered,
// one vm-drain barrier per tile (T3 minimal 2-phase). XOR-swizzled LDS on both sides.
// Mask staged to LDS in prologue. Per-step VMEM instr cut 4x vs per-wave fetching.

#define STAGE(BUF, T) do {                                                           \
    const int _kv = (T) << 5;                                                        \
    gl_lds16(Kp + (_kv + krow) * 64 + kswz, MEM + (BUF) * 4096 + wv * 1024);         \
    gl_lds16(Vp + vrow * 2048 + _kv + vswz, MEM + 8192 + (BUF) * 4096 + wv * 1024);  \
} while (0)

#define JOB(QF0, QF1, OO, M, L, QBASE) do {                                          \
    f32x4 s0 = {}, s1 = {};                                                          \
    s0 = __builtin_amdgcn_mfma_f32_16x16x32_bf16(kf00, QF0, s0, 0, 0, 0);            \
    s0 = __builtin_amdgcn_mfma_f32_16x16x32_bf16(kf01, QF1, s0, 0, 0, 0);            \
    s1 = __builtin_amdgcn_mfma_f32_16x16x32_bf16(kf10, QF0, s1, 0, 0, 0);            \
    s1 = __builtin_amdgcn_mfma_f32_16x16x32_bf16(kf11, QF1, s1, 0, 0, 0);            \
    float pr0[4], pr1[4];                                                            \
    if (kvb + 31 > (QBASE)) {                                                        \
        _Pragma("unroll")                                                            \
        for (int r = 0; r < 4; ++r) {                                                \
            float v0 = s0[r] + mv0[r];                                               \
            if (kvb + l4*4 + r > (QBASE) + l15) v0 = -1e30f;                         \
            pr0[r] = v0;                                                             \
            float v1 = s1[r] + mv1[r];                                               \
            if (kvb + 16 + l4*4 + r > (QBASE) + l15) v1 = -1e30f;                    \
            pr1[r] = v1;                                                             \
        }                                                                            \
    } else {                                                                         \
        _Pragma("unroll")                                                            \
        for (int r = 0; r < 4; ++r) { pr0[r] = s0[r] + mv0[r]; pr1[r] = s1[r] + mv1[r]; } \
    }                                                                                \
    float tl = fmaxf(fmaxf(fmaxf(pr0[0], pr0[1]), fmaxf(pr0[2], pr0[3])),            \
                     fmaxf(fmaxf(pr1[0], pr1[1]), fmaxf(pr1[2], pr1[3])));           \
    if (!__all(tl - (M) <= 8.0f)) {                                                  \
        float tm = tl;                                                               \
        tm = fmaxf(tm, __shfl_xor(tm, 16));                                          \
        tm = fmaxf(tm, __shfl_xor(tm, 32));                                          \
        float mn = fmaxf((M), tm);                                                   \
        float al = __expf((M) - mn);                                                 \
        M = mn; L *= al;                                                             \
        _Pragma("unroll")                                                            \
        for (int dt = 0; dt < 4; ++dt)                                               \
            _Pragma("unroll")                                                        \
            for (int r = 0; r < 4; ++r) OO[dt][r] *= al;                             \
    }                                                                                \
    _Pragma("unroll")                                                                \
    for (int r = 0; r < 4; ++r) { pr0[r] = __expf(pr0[r] - (M)); pr1[r] = __expf(pr1[r] - (M)); } \
    L += (pr0[0] + pr0[1]) + (pr0[2] + pr0[3])                                       \
       + (pr1[0] + pr1[1]) + (pr1[2] + pr1[3]);                                      \
    short4v w0, w1;                                                                  \
    _Pragma("unroll")                                                                \
    for (int r = 0; r < 4; ++r) { w0[r] = f2bf(pr0[r]); w1[r] = f2bf(pr1[r]); }      \
    *reinterpret_cast<short4v*>(pbw + l15*40 + l4*4)      = w0;                      \
    *reinterpret_cast<short4v*>(pbw + l15*40 + 16 + l4*4) = w1;                      \
    asm volatile("s_waitcnt lgkmcnt(0)" ::: "memory");                               \
    bf16x8 pf = *reinterpret_cast<const bf16x8*>(pbw + l15*40 + l4*8);               \
    OO[0] = __builtin_amdgcn_mfma_f32_16x16x32_bf16(vf0, pf, OO[0], 0, 0, 0);        \
    OO[1] = __builtin_amdgcn_mfma_f32_16x16x32_bf16(vf1, pf, OO[1], 0, 0, 0);        \
    OO[2] = __builtin_amdgcn_mfma_f32_16x16x32_bf16(vf2, pf, OO[2], 0, 0, 0);        \
    OO[3] = __builtin_amdgcn_mfma_f32_16x16x32_bf16(vf3, pf, OO[3], 0, 0, 0);        \
} while (0)

// LDS layout (bytes): K dbuf [2][4096] @0 | V dbuf [2][4096] @8192 | mask 8192 @16384
//                     | P buffers 4x1280 @24576  -> total 29696
__global__ __launch_bounds__(256) void attn(
        const short* __restrict__ Qb, const short* __restrict__ Kb,
        const short* __restrict__ Vt, const float* __restrict__ amask,
        float* __restrict__ outp) {
    __shared__ __align__(16) char MEM[29696];

    const int tid = threadIdx.x, wv = tid >> 6, lane = tid & 63;
    const int l15 = lane & 15, l4 = lane >> 4;
    // XCD-chunked swizzle: 512 blocks, HW id x -> work id (x%8)*64 + x/8
    const int wid = ((blockIdx.x & 7) << 6) + (blockIdx.x >> 3);
    const int bh = wid >> 4;                         // 32 (b,h), 16 blocks each... bh = wid>>4
    const int j  = wid & 15;
    const int i  = 4 * j + wv;                       // pair index 0..63
    const int b = bh >> 4, h = bh & 15;

    const short* Qp = Qb + bh * TT * HDD;
    const short* Kp = Kb + bh * TT * HDD;
    const short* Vp = Vt + bh * HDD * TT;
    const float* mp = amask + b * TT;
    short* pbw = (short*)(MEM + 24576 + wv * 1280);
    float* mlds = (float*)(MEM + 16384);

    const int qbaseA = (127 - i) << 4;
    const int qbaseB = i << 4;
    const int nktA = (qbaseA + 47) >> 5;
    const int nktB = (qbaseB + 47) >> 5;
    const int NT = ((127 - 4 * j) * 16 + 47) >> 5;   // block-uniform stream extent

    // staging lane geometry (per wave: K rows [wv*8, wv*8+8), V rows [wv*16, wv*16+16))
    const int krow = wv * 8 + (lane >> 3), kchunk = lane & 7;
    const int kswz = (kchunk ^ (krow & 7)) * 8;      // shorts
    const int vrow = wv * 16 + (lane >> 2), vchunk = lane & 3;
    const int vswz = (vchunk ^ (vrow & 3)) * 8;      // shorts

    // LDS read offsets (bytes)
    const int kb0 = l15 * 128 + ((l4 ^ (l15 & 7)) << 4);
    const int vb0 = l15 * 64 + ((l4 ^ (l15 & 3)) << 4);

    // prologue: mask -> LDS (whole row for this b)
    {
        int mi8 = tid * 8;
        float4 a = *reinterpret_cast<const float4*>(mp + mi8);
        float4 c = *reinterpret_cast<const float4*>(mp + mi8 + 4);
        *reinterpret_cast<float4*>(mlds + mi8) = a;
        *reinterpret_cast<float4*>(mlds + mi8 + 4) = c;
    }

    bf16x8 qfA0 = *reinterpret_cast<const bf16x8*>(Qp + (qbaseA + l15) * 64 + l4 * 8);
    bf16x8 qfA1 = *reinterpret_cast<const bf16x8*>(Qp + (qbaseA + l15) * 64 + 32 + l4 * 8);
    bf16x8 qfB0 = *reinterpret_cast<const bf16x8*>(Qp + (qbaseB + l15) * 64 + l4 * 8);
    bf16x8 qfB1 = *reinterpret_cast<const bf16x8*>(Qp + (qbaseB + l15) * 64 + 32 + l4 * 8);

    f32x4 OA[4] = {}, OB[4] = {};
    float MA = -1e30f, LA = 0.f, MB = -1e30f, LB = 0.f;

    STAGE(0, 0);
    __syncthreads();                                 // drains vmcnt+lgkmcnt (staging + mask)

    for (int t = 0; t < NT; ++t) {
        const int cur = t & 1;
        if (t + 1 < NT) STAGE(cur ^ 1, t + 1);       // async, lands by next barrier
        const int kvb = t << 5;
        if (t < nktA) {
            const char* Kcur = MEM + cur * 4096;
            const char* Vcur = MEM + 8192 + cur * 4096;
            bf16x8 kf00 = *reinterpret_cast<const bf16x8*>(Kcur + kb0);
            bf16x8 kf01 = *reinterpret_cast<const bf16x8*>(Kcur + (kb0 ^ 64));
            bf16x8 kf10 = *reinterpret_cast<const bf16x8*>(Kcur + 2048 + kb0);
            bf16x8 kf11 = *reinterpret_cast<const bf16x8*>(Kcur + 2048 + (kb0 ^ 64));
            bf16x8 vf0 = *reinterpret_cast<const bf16x8*>(Vcur + vb0);
            bf16x8 vf1 = *reinterpret_cast<const bf16x8*>(Vcur + 1024 + vb0);
            bf16x8 vf2 = *reinterpret_cast<const bf16x8*>(Vcur + 2048 + vb0);
            bf16x8 vf3 = *reinterpret_cast<const bf16x8*>(Vcur + 3072 + vb0);
            float4 mv0 = *reinterpret_cast<const float4*>(mlds + kvb + l4 * 4);
            float4 mv1 = *reinterpret_cast<const float4*>(mlds + kvb + 16 + l4 * 4);
            JOB(qfA0, qfA1, OA, MA, LA, qbaseA);
            if (t < nktB) JOB(qfB0, qfB1, OB, MB, LB, qbaseB);
        }
        __syncthreads();                             // full drain: staged t+1 ready, buf t free
    }

    // epilogue: reduce l across l4 groups, write O^T as float4 (t = qbase+l15, d chunk l4)
    LA += __shfl_xor(LA, 16); LA += __shfl_xor(LA, 32);
    LB += __shfl_xor(LB, 16); LB += __shfl_xor(LB, 32);
    {
        float invA = 1.0f / LA, invB = 1.0f / LB;
        int tA = qbaseA + l15, tB = qbaseB + l15;
#pragma unroll
        for (int dt = 0; dt < 4; ++dt) {
            float4 oa, ob;
            oa.x = OA[dt][0] * invA; oa.y = OA[dt][1] * invA;
            oa.z = OA[dt][2] * invA; oa.w = OA[dt][3] * invA;
            ob.x = OB[dt][0] * invB; ob.y = OB[dt][1] * invB;
            ob.z = OB[dt][2] * invB; ob.w = OB[dt][3] * invB;
            *reinterpret_cast<float4*>(outp + (b * 2048 + tA) * 1024 + h * 64 + dt * 16 + l4 * 4) = oa;
            *reinterpret_cast<float4*>(outp + (b * 2048 + tB) * 1024 + h * 64 + dt * 16 + l4 * 4) = ob;
        }
    }
}

extern "C" void kernel_launch(void* const* d_in, const int* in_sizes, int n_in,
                              void* d_out, int out_size, void* d_ws, size_t ws_size,
                              hipStream_t stream) {
    const float* hidden = (const float*)d_in[0];
    const float* amask  = (const float*)d_in[1];
    const float* Wq = (const float*)d_in[2];
    const float* bq = (const float*)d_in[3];
    const float* Aq = (const float*)d_in[4];
    const float* Bq = (const float*)d_in[5];
    const float* Wk = (const float*)d_in[6];
    const float* bk = (const float*)d_in[7];
    const float* Wv = (const float*)d_in[8];
    const float* bv = (const float*)d_in[9];
    const float* Av = (const float*)d_in[10];
    const float* Bv = (const float*)d_in[11];
    float* outp = (float*)d_out;

    char* ws = (char*)d_ws;
    short* Xbf = (short*)(ws);                 // 8 MB  [4096][1024] bf16
    short* Wqe = (short*)(ws + (8 << 20));     // 2 MB
    short* Wke = (short*)(ws + (10 << 20));    // 2 MB
    short* Wve = (short*)(ws + (12 << 20));    // 2 MB
    short* Qb  = (short*)(ws + (14 << 20));    // 8 MB  [b][h][t][d]
    short* Kb  = (short*)(ws + (22 << 20));    // 8 MB  [b][h][t][d]
    short* Vtb = (short*)(ws + (30 << 20));    // 8 MB  [b][h][d][t]

    cvt_hidden<<<4096, 256, 0, stream>>>(hidden, Xbf);
    prep_w<<<4096, 256, 0, stream>>>(Wq, Aq, Bq, Wqe, 1);
    prep_w<<<4096, 256, 0, stream>>>(Wk, nullptr, nullptr, Wke, 0);
    prep_w<<<4096, 256, 0, stream>>>(Wv, Av, Bv, Wve, 1);
    proj_gemm<<<dim3(8, 32, 3), 256, 0, stream>>>(Xbf, Wqe, Wke, Wve, bq, bk, bv, Qb, Kb, Vtb);
    attn<<<512, 256, 0, stream>>>(Qb, Kb, Vtb, amask, outp);
}

// Round 10
// 121.861 us; speedup vs baseline: 1.7729x; 1.1669x over previous
//
#include <hip/hip_runtime.h>
#include <hip/hip_bf16.h>

#define BB 2
#define TT 2048
#define DMM 1024
#define HH 16
#define HDD 64

typedef __attribute__((ext_vector_type(8))) short bf16x8;
typedef __attribute__((ext_vector_type(4))) short short4v;
typedef __attribute__((ext_vector_type(4))) float f32x4;

static __device__ __forceinline__ short f2bf(float f) {
    __hip_bfloat16 h = __float2bfloat16(f);
    return *reinterpret_cast<short*>(&h);
}

static __device__ __forceinline__ void gl_lds16(const void* g, void* l) {
    __builtin_amdgcn_global_load_lds(
        (const __attribute__((address_space(1))) void*)g,
        (__attribute__((address_space(3))) void*)l, 16, 0, 0);
}

// ---- hidden f32 -> bf16 (4 elems/thread) ----
__global__ void cvt_hidden(const float* __restrict__ x, short* __restrict__ y) {
    int i = blockIdx.x * 256 + threadIdx.x;          // 1M threads, 4M elems
    float4 v = reinterpret_cast<const float4*>(x)[i];
    short4v o;
    o[0] = f2bf(v.x); o[1] = f2bf(v.y); o[2] = f2bf(v.z); o[3] = f2bf(v.w);
    reinterpret_cast<short4v*>(y)[i] = o;
}

// ---- W_eff = W + 2.0 * B@A (Q,V) or plain W (K), cast bf16; grid.y = mode ----
__global__ void prep_w(const float* __restrict__ Wq, const float* __restrict__ Aq, const float* __restrict__ Bq,
                       const float* __restrict__ Wk,
                       const float* __restrict__ Wv, const float* __restrict__ Av, const float* __restrict__ Bv,
                       short* __restrict__ Wqe, short* __restrict__ Wke, short* __restrict__ Wve) {
    const int mode = blockIdx.y;
    const float* W = (mode == 0) ? Wq : (mode == 1) ? Wk : Wv;
    const float* A = (mode == 0) ? Aq : Av;
    const float* Bm = (mode == 0) ? Bq : Bv;
    short* outp = (mode == 0) ? Wqe : (mode == 1) ? Wke : Wve;
    int idx = blockIdx.x * 256 + threadIdx.x;        // 1M elems
    int n = idx >> 10, k = idx & 1023;
    float v = W[idx];
    if (mode != 1) {
        float s = 0.f;
#pragma unroll
        for (int r = 0; r < 8; ++r) s += Bm[n * 8 + r] * A[r * 1024 + k];
        v += 2.0f * s;
    }
    outp[idx] = f2bf(v);
}

// ---- projection GEMM (m97-style): global_load_lds staging, swizzled LDS ----
// z = 0: Q (scale 0.125, [b][h][t][d]); z=1: K (same); z=2: V -> [b][h][d][t]
// Modes 0/1 compute C^T (operand swap) so each lane holds 4 consecutive d -> 8B stores.
// Mode 2 computes C so each lane holds 4 consecutive t (V^T layout) -> 8B stores.
__global__ __launch_bounds__(256) void proj_gemm(
        const short* __restrict__ Xbf,
        const short* __restrict__ Wq, const short* __restrict__ Wk, const short* __restrict__ Wv,
        const float* __restrict__ bq, const float* __restrict__ bk, const float* __restrict__ bv,
        short* __restrict__ Qb, short* __restrict__ Kb, short* __restrict__ Vtb) {
    __shared__ __align__(16) char As[128 * 128];     // 128 rows x 64 bf16 (128B), swizzled
    __shared__ __align__(16) char Bs[128 * 128];

    const int mode = blockIdx.z;
    const short* Wbf = (mode == 0) ? Wq : (mode == 1) ? Wk : Wv;
    const float* bias = (mode == 0) ? bq : (mode == 1) ? bk : bv;
    short* outp = (mode == 0) ? Qb : (mode == 1) ? Kb : Vtb;
    const float scale = (mode == 0) ? 0.125f : 1.0f;  // HD^-0.5 folded into Q

    const int tid = threadIdx.x;
    const int wave = tid >> 6, lane = tid & 63;
    const int l15 = lane & 15, l4 = lane >> 4;
    const int m0 = blockIdx.y * 128, n0 = blockIdx.x * 128;
    const int wm = (wave >> 1) * 64, wn = (wave & 1) * 64;

    // staging geometry: wave stages rows [wave*32, wave*32+32), 4 x 1KB linear chunks.
    // LDS linear (row*128 + c*16); read swizzle is c^(row&7), so pre-swizzle SOURCE chunk.
    const int lrow = lane >> 3;                      // 0..7 (row within 1KB chunk, == row&7)
    const int lchunk = lane & 7;                     // 16B chunk
    const int srcoff = (lchunk ^ lrow) * 8;          // shorts
    char* ldsA = As + wave * 4096;
    char* ldsB = Bs + wave * 4096;

    // operand roles: modes 0/1 swap (features first -> C row = d); mode 2 normal
    const char* P1 = (mode == 2) ? As : Bs;
    const char* P2 = (mode == 2) ? Bs : As;
    const int o1 = (mode == 2) ? wm : wn;
    const int o2 = (mode == 2) ? wn : wm;

    f32x4 acc[4][4] = {};

    for (int k0 = 0; k0 < 1024; k0 += 64) {
        __syncthreads();                             // previous compute done; LDS free
#pragma unroll
        for (int i = 0; i < 4; ++i) {
            int row = wave * 32 + i * 8 + lrow;
            gl_lds16(Xbf + (m0 + row) * 1024 + k0 + srcoff, ldsA + i * 1024);
            gl_lds16(Wbf + (n0 + row) * 1024 + k0 + srcoff, ldsB + i * 1024);
        }
        __syncthreads();                             // vm drain: staged tile ready
#pragma unroll
        for (int kk = 0; kk < 2; ++kk) {
            const int colb = kk * 64 + l4 * 16;
            bf16x8 f1[4], f2[4];
#pragma unroll
            for (int x = 0; x < 4; ++x) {
                int r1 = o1 + x * 16 + l15;
                f1[x] = *reinterpret_cast<const bf16x8*>(P1 + ((r1 * 128 + colb) ^ ((r1 & 7) << 4)));
                int r2 = o2 + x * 16 + l15;
                f2[x] = *reinterpret_cast<const bf16x8*>(P2 + ((r2 * 128 + colb) ^ ((r2 & 7) << 4)));
            }
#pragma unroll
            for (int x = 0; x < 4; ++x)
#pragma unroll
                for (int y = 0; y < 4; ++y)
                    acc[x][y] = __builtin_amdgcn_mfma_f32_16x16x32_bf16(f1[x], f2[y], acc[x][y], 0, 0, 0);
        }
    }

    // epilogue: packed 8B stores
    if (mode != 2) {
        // C^T: row-space = features (wn), col-space = tokens (wm)
#pragma unroll
        for (int x = 0; x < 4; ++x) {
            int gnb = n0 + wn + x * 16 + l4 * 4;     // 4 consecutive features
            int hh = gnb >> 6, d = gnb & 63;
            float4 bv4 = *reinterpret_cast<const float4*>(bias + gnb);
#pragma unroll
            for (int y = 0; y < 4; ++y) {
                int gm = m0 + wm + y * 16 + l15;
                int bb = gm >> 11, t = gm & 2047;
                short4v o;
                o[0] = f2bf((acc[x][y][0] + bv4.x) * scale);
                o[1] = f2bf((acc[x][y][1] + bv4.y) * scale);
                o[2] = f2bf((acc[x][y][2] + bv4.z) * scale);
                o[3] = f2bf((acc[x][y][3] + bv4.w) * scale);
                *reinterpret_cast<short4v*>(outp + ((bb * 16 + hh) * 2048 + t) * 64 + d) = o;
            }
        }
    } else {
        // C: row-space = tokens (wm), col-space = features (wn); V^T [d][t]
#pragma unroll
        for (int x = 0; x < 4; ++x) {
            int gmb = m0 + wm + x * 16 + l4 * 4;     // 4 consecutive tokens
            int bb = gmb >> 11, t = gmb & 2047;
#pragma unroll
            for (int y = 0; y < 4; ++y) {
                int gn = n0 + wn + y * 16 + l15;
                int hh = gn >> 6, d = gn & 63;
                float bvs = bias[gn];
                short4v o;
                o[0] = f2bf(acc[x][y][0] + bvs);
                o[1] = f2bf(acc[x][y][1] + bvs);
                o[2] = f2bf(acc[x][y][2] + bvs);
                o[3] = f2bf(acc[x][y][3] + bvs);
                *reinterpret_cast<short4v*>(outp + ((bb * 16 + hh) * 64 + d) * 2048 + t) = o;
            }
        }
    }
}

// ---- flash attention v7: block-shared LDS K/V staging (global_load_lds), swapped-QK ----
// (unchanged from round 9 — attn is no longer the dominant dispatch)

#define STAGE(BUF, T) do {                                                           \
    const int _kv = (T) << 5;                                                        \
    gl_lds16(Kp + (_kv + krow) * 64 + kswz, MEM + (BUF) * 4096 + wv * 1024);         \
    gl_lds16(Vp + vrow * 2048 + _kv + vswz, MEM + 8192 + (BUF) * 4096 + wv * 1024);  \
} while (0)

#define JOB(QF0, QF1, OO, M, L, QBASE) do {                                          \
    f32x4 s0 = {}, s1 = {};                                                          \
    s0 = __builtin_amdgcn_mfma_f32_16x16x32_bf16(kf00, QF0, s0, 0, 0, 0);            \
    s0 = __builtin_amdgcn_mfma_f32_16x16x32_bf16(kf01, QF1, s0, 0, 0, 0);            \
    s1 = __builtin_amdgcn_mfma_f32_16x16x32_bf16(kf10, QF0, s1, 0, 0, 0);            \
    s1 = __builtin_amdgcn_mfma_f32_16x16x32_bf16(kf11, QF1, s1, 0, 0, 0);            \
    float pr0[4], pr1[4];                                                            \
    if (kvb + 31 > (QBASE)) {                                                        \
        _Pragma("unroll")                                                            \
        for (int r = 0; r < 4; ++r) {                                                \
            float v0 = s0[r] + mv0[r];                                               \
            if (kvb + l4*4 + r > (QBASE) + l15) v0 = -1e30f;                         \
            pr0[r] = v0;                                                             \
            float v1 = s1[r] + mv1[r];                                               \
            if (kvb + 16 + l4*4 + r > (QBASE) + l15) v1 = -1e30f;                    \
            pr1[r] = v1;                                                             \
        }                                                                            \
    } else {                                                                         \
        _Pragma("unroll")                                                            \
        for (int r = 0; r < 4; ++r) { pr0[r] = s0[r] + mv0[r]; pr1[r] = s1[r] + mv1[r]; } \
    }                                                                                \
    float tl = fmaxf(fmaxf(fmaxf(pr0[0], pr0[1]), fmaxf(pr0[2], pr0[3])),            \
                     fmaxf(fmaxf(pr1[0], pr1[1]), fmaxf(pr1[2], pr1[3])));           \
    if (!__all(tl - (M) <= 8.0f)) {                                                  \
        float tm = tl;                                                               \
        tm = fmaxf(tm, __shfl_xor(tm, 16));                                          \
        tm = fmaxf(tm, __shfl_xor(tm, 32));                                          \
        float mn = fmaxf((M), tm);                                                   \
        float al = __expf((M) - mn);                                                 \
        M = mn; L *= al;                                                             \
        _Pragma("unroll")                                                            \
        for (int dt = 0; dt < 4; ++dt)                                               \
            _Pragma("unroll")                                                        \
            for (int r = 0; r < 4; ++r) OO[dt][r] *= al;                             \
    }                                                                                \
    _Pragma("unroll")                                                                \
    for (int r = 0; r < 4; ++r) { pr0[r] = __expf(pr0[r] - (M)); pr1[r] = __expf(pr1[r] - (M)); } \
    L += (pr0[0] + pr0[1]) + (pr0[2] + pr0[3])                                       \
       + (pr1[0] + pr1[1]) + (pr1[2] + pr1[3]);                                      \
    short4v w0, w1;                                                                  \
    _Pragma("unroll")                                                                \
    for (int r = 0; r < 4; ++r) { w0[r] = f2bf(pr0[r]); w1[r] = f2bf(pr1[r]); }      \
    *reinterpret_cast<short4v*>(pbw + l15*40 + l4*4)      = w0;                      \
    *reinterpret_cast<short4v*>(pbw + l15*40 + 16 + l4*4) = w1;                      \
    asm volatile("s_waitcnt lgkmcnt(0)" ::: "memory");                               \
    bf16x8 pf = *reinterpret_cast<const bf16x8*>(pbw + l15*40 + l4*8);               \
    OO[0] = __builtin_amdgcn_mfma_f32_16x16x32_bf16(vf0, pf, OO[0], 0, 0, 0);        \
    OO[1] = __builtin_amdgcn_mfma_f32_16x16x32_bf16(vf1, pf, OO[1], 0, 0, 0);        \
    OO[2] = __builtin_amdgcn_mfma_f32_16x16x32_bf16(vf2, pf, OO[2], 0, 0, 0);        \
    OO[3] = __builtin_amdgcn_mfma_f32_16x16x32_bf16(vf3, pf, OO[3], 0, 0, 0);        \
} while (0)

// LDS layout (bytes): K dbuf [2][4096] @0 | V dbuf [2][4096] @8192 | mask 8192 @16384
//                     | P buffers 4x1280 @24576  -> total 29696
__global__ __launch_bounds__(256) void attn(
        const short* __restrict__ Qb, const short* __restrict__ Kb,
        const short* __restrict__ Vt, const float* __restrict__ amask,
        float* __restrict__ outp) {
    __shared__ __align__(16) char MEM[29696];

    const int tid = threadIdx.x, wv = tid >> 6, lane = tid & 63;
    const int l15 = lane & 15, l4 = lane >> 4;
    // XCD-chunked swizzle: 512 blocks, HW id x -> work id (x%8)*64 + x/8
    const int wid = ((blockIdx.x & 7) << 6) + (blockIdx.x >> 3);
    const int bh = wid >> 4;                         // 32 (b,h), 16 blocks each
    const int j  = wid & 15;
    const int i  = 4 * j + wv;                       // pair index 0..63
    const int b = bh >> 4, h = bh & 15;

    const short* Qp = Qb + bh * TT * HDD;
    const short* Kp = Kb + bh * TT * HDD;
    const short* Vp = Vt + bh * HDD * TT;
    const float* mp = amask + b * TT;
    short* pbw = (short*)(MEM + 24576 + wv * 1280);
    float* mlds = (float*)(MEM + 16384);

    const int qbaseA = (127 - i) << 4;
    const int qbaseB = i << 4;
    const int nktA = (qbaseA + 47) >> 5;
    const int nktB = (qbaseB + 47) >> 5;
    const int NT = ((127 - 4 * j) * 16 + 47) >> 5;   // block-uniform stream extent

    // staging lane geometry (per wave: K rows [wv*8, wv*8+8), V rows [wv*16, wv*16+16))
    const int krow = wv * 8 + (lane >> 3), kchunk = lane & 7;
    const int kswz = (kchunk ^ (krow & 7)) * 8;      // shorts
    const int vrow = wv * 16 + (lane >> 2), vchunk = lane & 3;
    const int vswz = (vchunk ^ (vrow & 3)) * 8;      // shorts

    // LDS read offsets (bytes)
    const int kb0 = l15 * 128 + ((l4 ^ (l15 & 7)) << 4);
    const int vb0 = l15 * 64 + ((l4 ^ (l15 & 3)) << 4);

    // prologue: mask -> LDS (whole row for this b)
    {
        int mi8 = tid * 8;
        float4 a = *reinterpret_cast<const float4*>(mp + mi8);
        float4 c = *reinterpret_cast<const float4*>(mp + mi8 + 4);
        *reinterpret_cast<float4*>(mlds + mi8) = a;
        *reinterpret_cast<float4*>(mlds + mi8 + 4) = c;
    }

    bf16x8 qfA0 = *reinterpret_cast<const bf16x8*>(Qp + (qbaseA + l15) * 64 + l4 * 8);
    bf16x8 qfA1 = *reinterpret_cast<const bf16x8*>(Qp + (qbaseA + l15) * 64 + 32 + l4 * 8);
    bf16x8 qfB0 = *reinterpret_cast<const bf16x8*>(Qp + (qbaseB + l15) * 64 + l4 * 8);
    bf16x8 qfB1 = *reinterpret_cast<const bf16x8*>(Qp + (qbaseB + l15) * 64 + 32 + l4 * 8);

    f32x4 OA[4] = {}, OB[4] = {};
    float MA = -1e30f, LA = 0.f, MB = -1e30f, LB = 0.f;

    STAGE(0, 0);
    __syncthreads();                                 // drains vmcnt+lgkmcnt (staging + mask)

    for (int t = 0; t < NT; ++t) {
        const int cur = t & 1;
        if (t + 1 < NT) STAGE(cur ^ 1, t + 1);       // async, lands by next barrier
        const int kvb = t << 5;
        if (t < nktA) {
            const char* Kcur = MEM + cur * 4096;
            const char* Vcur = MEM + 8192 + cur * 4096;
            bf16x8 kf00 = *reinterpret_cast<const bf16x8*>(Kcur + kb0);
            bf16x8 kf01 = *reinterpret_cast<const bf16x8*>(Kcur + (kb0 ^ 64));
            bf16x8 kf10 = *reinterpret_cast<const bf16x8*>(Kcur + 2048 + kb0);
            bf16x8 kf11 = *reinterpret_cast<const bf16x8*>(Kcur + 2048 + (kb0 ^ 64));
            bf16x8 vf0 = *reinterpret_cast<const bf16x8*>(Vcur + vb0);
            bf16x8 vf1 = *reinterpret_cast<const bf16x8*>(Vcur + 1024 + vb0);
            bf16x8 vf2 = *reinterpret_cast<const bf16x8*>(Vcur + 2048 + vb0);
            bf16x8 vf3 = *reinterpret_cast<const bf16x8*>(Vcur + 3072 + vb0);
            float4 mv0 = *reinterpret_cast<const float4*>(mlds + kvb + l4 * 4);
            float4 mv1 = *reinterpret_cast<const float4*>(mlds + kvb + 16 + l4 * 4);
            JOB(qfA0, qfA1, OA, MA, LA, qbaseA);
            if (t < nktB) JOB(qfB0, qfB1, OB, MB, LB, qbaseB);
        }
        __syncthreads();                             // full drain: staged t+1 ready, buf t free
    }

    // epilogue: reduce l across l4 groups, write O^T as float4 (t = qbase+l15, d chunk l4)
    LA += __shfl_xor(LA, 16); LA += __shfl_xor(LA, 32);
    LB += __shfl_xor(LB, 16); LB += __shfl_xor(LB, 32);
    {
        float invA = 1.0f / LA, invB = 1.0f / LB;
        int tA = qbaseA + l15, tB = qbaseB + l15;
#pragma unroll
        for (int dt = 0; dt < 4; ++dt) {
            float4 oa, ob;
            oa.x = OA[dt][0] * invA; oa.y = OA[dt][1] * invA;
            oa.z = OA[dt][2] * invA; oa.w = OA[dt][3] * invA;
            ob.x = OB[dt][0] * invB; ob.y = OB[dt][1] * invB;
            ob.z = OB[dt][2] * invB; ob.w = OB[dt][3] * invB;
            *reinterpret_cast<float4*>(outp + (b * 2048 + tA) * 1024 + h * 64 + dt * 16 + l4 * 4) = oa;
            *reinterpret_cast<float4*>(outp + (b * 2048 + tB) * 1024 + h * 64 + dt * 16 + l4 * 4) = ob;
        }
    }
}

extern "C" void kernel_launch(void* const* d_in, const int* in_sizes, int n_in,
                              void* d_out, int out_size, void* d_ws, size_t ws_size,
                              hipStream_t stream) {
    const float* hidden = (const float*)d_in[0];
    const float* amask  = (const float*)d_in[1];
    const float* Wq = (const float*)d_in[2];
    const float* bq = (const float*)d_in[3];
    const float* Aq = (const float*)d_in[4];
    const float* Bq = (const float*)d_in[5];
    const float* Wk = (const float*)d_in[6];
    const float* bk = (const float*)d_in[7];
    const float* Wv = (const float*)d_in[8];
    const float* bv = (const float*)d_in[9];
    const float* Av = (const float*)d_in[10];
    const float* Bv = (const float*)d_in[11];
    float* outp = (float*)d_out;

    char* ws = (char*)d_ws;
    short* Xbf = (short*)(ws);                 // 8 MB  [4096][1024] bf16
    short* Wqe = (short*)(ws + (8 << 20));     // 2 MB
    short* Wke = (short*)(ws + (10 << 20));    // 2 MB
    short* Wve = (short*)(ws + (12 << 20));    // 2 MB
    short* Qb  = (short*)(ws + (14 << 20));    // 8 MB  [b][h][t][d]
    short* Kb  = (short*)(ws + (22 << 20));    // 8 MB  [b][h][t][d]
    short* Vtb = (short*)(ws + (30 << 20));    // 8 MB  [b][h][d][t]

    cvt_hidden<<<4096, 256, 0, stream>>>(hidden, Xbf);
    prep_w<<<dim3(4096, 3), 256, 0, stream>>>(Wq, Aq, Bq, Wk, Wv, Av, Bv, Wqe, Wke, Wve);
    proj_gemm<<<dim3(8, 32, 3), 256, 0, stream>>>(Xbf, Wqe, Wke, Wve, bq, bk, bv, Qb, Kb, Vtb);
    attn<<<512, 256, 0, stream>>>(Qb, Kb, Vtb, amask, outp);
}

// Round 12
// 117.492 us; speedup vs baseline: 1.8388x; 1.0372x over previous
//
#include <hip/hip_runtime.h>
#include <hip/hip_bf16.h>

#define BB 2
#define TT 2048
#define DMM 1024
#define HH 16
#define HDD 64

typedef __attribute__((ext_vector_type(8))) short bf16x8;
typedef __attribute__((ext_vector_type(4))) short short4v;
typedef __attribute__((ext_vector_type(4))) float f32x4;

static __device__ __forceinline__ short f2bf(float f) {
    __hip_bfloat16 h = __float2bfloat16(f);
    return *reinterpret_cast<short*>(&h);
}

static __device__ __forceinline__ void gl_lds16(const void* g, void* l) {
    __builtin_amdgcn_global_load_lds(
        (const __attribute__((address_space(1))) void*)g,
        (__attribute__((address_space(3))) void*)l, 16, 0, 0);
}

// ---- hidden f32 -> bf16 (4 elems/thread) ----
__global__ void cvt_hidden(const float* __restrict__ x, short* __restrict__ y) {
    int i = blockIdx.x * 256 + threadIdx.x;          // 1M threads, 4M elems
    float4 v = reinterpret_cast<const float4*>(x)[i];
    short4v o;
    o[0] = f2bf(v.x); o[1] = f2bf(v.y); o[2] = f2bf(v.z); o[3] = f2bf(v.w);
    reinterpret_cast<short4v*>(y)[i] = o;
}

// ---- W_eff = W + 2.0 * B@A (Q,V) or plain W (K), cast bf16; grid.y = mode ----
__global__ void prep_w(const float* __restrict__ Wq, const float* __restrict__ Aq, const float* __restrict__ Bq,
                       const float* __restrict__ Wk,
                       const float* __restrict__ Wv, const float* __restrict__ Av, const float* __restrict__ Bv,
                       short* __restrict__ Wqe, short* __restrict__ Wke, short* __restrict__ Wve) {
    const int mode = blockIdx.y;
    const float* W = (mode == 0) ? Wq : (mode == 1) ? Wk : Wv;
    const float* A = (mode == 0) ? Aq : Av;
    const float* Bm = (mode == 0) ? Bq : Bv;
    short* outp = (mode == 0) ? Wqe : (mode == 1) ? Wke : Wve;
    int idx = blockIdx.x * 256 + threadIdx.x;        // 1M elems
    int n = idx >> 10, k = idx & 1023;
    float v = W[idx];
    if (mode != 1) {
        float s = 0.f;
#pragma unroll
        for (int r = 0; r < 8; ++r) s += Bm[n * 8 + r] * A[r * 1024 + k];
        v += 2.0f * s;
    }
    outp[idx] = f2bf(v);
}

// ---- projection GEMM (m97-style): global_load_lds staging, swizzled LDS ----
// z = 0: Q (scale 0.125, [b][h][t][d]); z=1: K (same); z=2: V -> [b][h][d][t]
__global__ __launch_bounds__(256) void proj_gemm(
        const short* __restrict__ Xbf,
        const short* __restrict__ Wq, const short* __restrict__ Wk, const short* __restrict__ Wv,
        const float* __restrict__ bq, const float* __restrict__ bk, const float* __restrict__ bv,
        short* __restrict__ Qb, short* __restrict__ Kb, short* __restrict__ Vtb) {
    __shared__ __align__(16) char As[128 * 128];     // 128 rows x 64 bf16 (128B), swizzled
    __shared__ __align__(16) char Bs[128 * 128];

    const int mode = blockIdx.z;
    const short* Wbf = (mode == 0) ? Wq : (mode == 1) ? Wk : Wv;
    const float* bias = (mode == 0) ? bq : (mode == 1) ? bk : bv;
    short* outp = (mode == 0) ? Qb : (mode == 1) ? Kb : Vtb;
    const float scale = (mode == 0) ? 0.125f : 1.0f;  // HD^-0.5 folded into Q

    const int tid = threadIdx.x;
    const int wave = tid >> 6, lane = tid & 63;
    const int l15 = lane & 15, l4 = lane >> 4;
    const int m0 = blockIdx.y * 128, n0 = blockIdx.x * 128;
    const int wm = (wave >> 1) * 64, wn = (wave & 1) * 64;

    const int lrow = lane >> 3;                      // 0..7
    const int lchunk = lane & 7;                     // 16B chunk
    const int srcoff = (lchunk ^ lrow) * 8;          // shorts
    char* ldsA = As + wave * 4096;
    char* ldsB = Bs + wave * 4096;

    const char* P1 = (mode == 2) ? As : Bs;
    const char* P2 = (mode == 2) ? Bs : As;
    const int o1 = (mode == 2) ? wm : wn;
    const int o2 = (mode == 2) ? wn : wm;

    f32x4 acc[4][4] = {};

    for (int k0 = 0; k0 < 1024; k0 += 64) {
        __syncthreads();
#pragma unroll
        for (int i = 0; i < 4; ++i) {
            int row = wave * 32 + i * 8 + lrow;
            gl_lds16(Xbf + (m0 + row) * 1024 + k0 + srcoff, ldsA + i * 1024);
            gl_lds16(Wbf + (n0 + row) * 1024 + k0 + srcoff, ldsB + i * 1024);
        }
        __syncthreads();
#pragma unroll
        for (int kk = 0; kk < 2; ++kk) {
            const int colb = kk * 64 + l4 * 16;
            bf16x8 f1[4], f2[4];
#pragma unroll
            for (int x = 0; x < 4; ++x) {
                int r1 = o1 + x * 16 + l15;
                f1[x] = *reinterpret_cast<const bf16x8*>(P1 + ((r1 * 128 + colb) ^ ((r1 & 7) << 4)));
                int r2 = o2 + x * 16 + l15;
                f2[x] = *reinterpret_cast<const bf16x8*>(P2 + ((r2 * 128 + colb) ^ ((r2 & 7) << 4)));
            }
#pragma unroll
            for (int x = 0; x < 4; ++x)
#pragma unroll
                for (int y = 0; y < 4; ++y)
                    acc[x][y] = __builtin_amdgcn_mfma_f32_16x16x32_bf16(f1[x], f2[y], acc[x][y], 0, 0, 0);
        }
    }

    if (mode != 2) {
#pragma unroll
        for (int x = 0; x < 4; ++x) {
            int gnb = n0 + wn + x * 16 + l4 * 4;
            int hh = gnb >> 6, d = gnb & 63;
            float4 bv4 = *reinterpret_cast<const float4*>(bias + gnb);
#pragma unroll
            for (int y = 0; y < 4; ++y) {
                int gm = m0 + wm + y * 16 + l15;
                int bb = gm >> 11, t = gm & 2047;
                short4v o;
                o[0] = f2bf((acc[x][y][0] + bv4.x) * scale);
                o[1] = f2bf((acc[x][y][1] + bv4.y) * scale);
                o[2] = f2bf((acc[x][y][2] + bv4.z) * scale);
                o[3] = f2bf((acc[x][y][3] + bv4.w) * scale);
                *reinterpret_cast<short4v*>(outp + ((bb * 16 + hh) * 2048 + t) * 64 + d) = o;
            }
        }
    } else {
#pragma unroll
        for (int x = 0; x < 4; ++x) {
            int gmb = m0 + wm + x * 16 + l4 * 4;
            int bb = gmb >> 11, t = gmb & 2047;
#pragma unroll
            for (int y = 0; y < 4; ++y) {
                int gn = n0 + wn + y * 16 + l15;
                int hh = gn >> 6, d = gn & 63;
                float bvs = bias[gn];
                short4v o;
                o[0] = f2bf(acc[x][y][0] + bvs);
                o[1] = f2bf(acc[x][y][1] + bvs);
                o[2] = f2bf(acc[x][y][2] + bvs);
                o[3] = f2bf(acc[x][y][3] + bvs);
                *reinterpret_cast<short4v*>(outp + ((bb * 16 + hh) * 64 + d) * 2048 + t) = o;
            }
        }
    }
}

// ---- flash attention v8: key-slice split pairs, no P roundtrip (K=16 PV) ----
// 1024 blocks x 4 waves = 4096 waves (16/CU). Block = (bh, j): pairs i = 2j+p.
// Wave (p, s): pair p, key-slice s (16 keys of each staged 32-key tile).
// QK: 2x mfma 16x16x32 on slice -> C frag (lane: q=l15, key=l4*4+r) feeds the
// K=16 PV B-operand DIRECTLY (same lane layout) -> no LDS P buffer at all.
// Disjoint-key merge between slice waves at the end (LDS, reuses dead K/V region).

#define STAGE(BUF, T) do {                                                           \
    const int _kv = (T) << 5;                                                        \
    gl_lds16(Kp + (_kv + krow) * 64 + kswz, MEM + (BUF) * 4096 + wv * 1024);         \
    gl_lds16(Vp + vrow * 2048 + _kv + vswz, MEM + 8192 + (BUF) * 4096 + wv * 1024);  \
} while (0)

#define SLICEJOB(QF0, QF1, OO, M, L, QBASE) do {                                     \
    f32x4 ss = {};                                                                   \
    ss = __builtin_amdgcn_mfma_f32_16x16x32_bf16(kf0, QF0, ss, 0, 0, 0);             \
    ss = __builtin_amdgcn_mfma_f32_16x16x32_bf16(kf1, QF1, ss, 0, 0, 0);             \
    float pr[4];                                                                     \
    if (kvs + 15 > (QBASE)) {                                                        \
        _Pragma("unroll")                                                            \
        for (int r = 0; r < 4; ++r) {                                                \
            float v = ss[r] + mv[r];                                                 \
            if (kvs + l4*4 + r > (QBASE) + l15) v = -1e30f;                          \
            pr[r] = v;                                                               \
        }                                                                            \
    } else {                                                                         \
        _Pragma("unroll")                                                            \
        for (int r = 0; r < 4; ++r) pr[r] = ss[r] + mv[r];                           \
    }                                                                                \
    float tl = fmaxf(fmaxf(pr[0], pr[1]), fmaxf(pr[2], pr[3]));                      \
    if (!__all(tl - (M) <= 8.0f)) {                                                  \
        float tm = tl;                                                               \
        tm = fmaxf(tm, __shfl_xor(tm, 16));                                          \
        tm = fmaxf(tm, __shfl_xor(tm, 32));                                          \
        float mn = fmaxf((M), tm);                                                   \
        float al = __expf((M) - mn);                                                 \
        M = mn; L *= al;                                                             \
        _Pragma("unroll")                                                            \
        for (int dt = 0; dt < 4; ++dt)                                               \
            _Pragma("unroll")                                                        \
            for (int r = 0; r < 4; ++r) OO[dt][r] *= al;                             \
    }                                                                                \
    _Pragma("unroll")                                                                \
    for (int r = 0; r < 4; ++r) pr[r] = __expf(pr[r] - (M));                         \
    L += (pr[0] + pr[1]) + (pr[2] + pr[3]);                                          \
    short4v pa;                                                                      \
    _Pragma("unroll")                                                                \
    for (int r = 0; r < 4; ++r) pa[r] = f2bf(pr[r]);                                 \
    _Pragma("unroll")                                                                \
    for (int dt = 0; dt < 4; ++dt)                                                   \
        OO[dt] = __builtin_amdgcn_mfma_f32_16x16x16bf16_1k(vf[dt], pa, OO[dt], 0, 0, 0); \
} while (0)

// LDS (bytes): K dbuf [2][4096] @0 | V dbuf [2][4096] @8192 | mask 8192 @16384 = 24576
// merge regions reuse @0 after the stream loop (2 pairs x 64 lanes x 160B = 20480)
__global__ __launch_bounds__(256, 4) void attn(
        const short* __restrict__ Qb, const short* __restrict__ Kb,
        const short* __restrict__ Vt, const float* __restrict__ amask,
        float* __restrict__ outp) {
    __shared__ __align__(16) char MEM[24576];

    const int tid = threadIdx.x, wv = tid >> 6, lane = tid & 63;
    const int l15 = lane & 15, l4 = lane >> 4;
    // XCD-chunked swizzle: 1024 blocks, HW id x -> work id (x%8)*128 + x/8
    const int wid = ((blockIdx.x & 7) << 7) + (blockIdx.x >> 3);
    const int bh = wid >> 5;                         // 32 (b,h)
    const int j  = wid & 31;                         // 32 pair-groups
    const int p  = wv & 1;                           // pair in block
    const int s  = wv >> 1;                          // key-slice
    const int i  = 2 * j + p;                        // pair index 0..63
    const int b = bh >> 4, h = bh & 15;

    const short* Qp = Qb + bh * TT * HDD;
    const short* Kp = Kb + bh * TT * HDD;
    const short* Vp = Vt + bh * HDD * TT;
    const float* mp = amask + b * TT;
    float* mlds = (float*)(MEM + 16384);

    const int qbaseA = (127 - i) << 4;
    const int qbaseB = i << 4;
    const int nkA = ((qbaseA + 15 - 16 * s) >> 5) + 1;   // slice-aware causal bounds
    const int nkB = ((qbaseB + 15 - 16 * s) >> 5) + 1;   // (0 when slice fully masked)
    const int NT = ((127 - 2 * j) * 16 + 47) >> 5;       // block stream extent

    // staging lane geometry (wave: K rows [wv*8,+8), V rows [wv*16,+16))
    const int krow = wv * 8 + (lane >> 3);
    const int kswz = ((lane & 7) ^ (lane >> 3)) * 8;     // shorts
    const int vrow = wv * 16 + (lane >> 2);
    const int vswz = ((lane & 3) ^ ((lane >> 2) & 3)) * 8;

    // LDS read offsets (bytes)
    const int kb0 = (16 * s + l15) * 128 + ((l4 ^ (l15 & 7)) << 4);
    const int vb0 = l15 * 64 + ((((2 * s) + (l4 >> 1)) ^ (l15 & 3)) << 4) + (l4 & 1) * 8;

    // prologue: mask -> LDS (whole row for this b)
    {
        int mi8 = tid * 8;
        float4 a = *reinterpret_cast<const float4*>(mp + mi8);
        float4 c = *reinterpret_cast<const float4*>(mp + mi8 + 4);
        *reinterpret_cast<float4*>(mlds + mi8) = a;
        *reinterpret_cast<float4*>(mlds + mi8 + 4) = c;
    }

    bf16x8 qfA0 = *reinterpret_cast<const bf16x8*>(Qp + (qbaseA + l15) * 64 + l4 * 8);
    bf16x8 qfA1 = *reinterpret_cast<const bf16x8*>(Qp + (qbaseA + l15) * 64 + 32 + l4 * 8);
    bf16x8 qfB0 = *reinterpret_cast<const bf16x8*>(Qp + (qbaseB + l15) * 64 + l4 * 8);
    bf16x8 qfB1 = *reinterpret_cast<const bf16x8*>(Qp + (qbaseB + l15) * 64 + 32 + l4 * 8);

    f32x4 OA[4] = {}, OB[4] = {};
    float MA = -1e30f, LA = 0.f, MB = -1e30f, LB = 0.f;

    STAGE(0, 0);
    __syncthreads();                                 // staging + mask drained

    for (int t = 0; t < NT; ++t) {
        const int cur = t & 1;
        if (t + 1 < NT) STAGE(cur ^ 1, t + 1);       // async, lands by next barrier
        if (t < nkA) {
            const char* Kcur = MEM + cur * 4096;
            const char* Vcur = MEM + 8192 + cur * 4096;
            bf16x8 kf0 = *reinterpret_cast<const bf16x8*>(Kcur + kb0);
            bf16x8 kf1 = *reinterpret_cast<const bf16x8*>(Kcur + (kb0 ^ 64));
            short4v vf[4];
#pragma unroll
            for (int dt = 0; dt < 4; ++dt)
                vf[dt] = *reinterpret_cast<const short4v*>(Vcur + dt * 1024 + vb0);
            const int kvs = (t << 5) + 16 * s;
            float4 mv = *reinterpret_cast<const float4*>(mlds + kvs + l4 * 4);
            SLICEJOB(qfA0, qfA1, OA, MA, LA, qbaseA);
            if (t < nkB) SLICEJOB(qfB0, qfB1, OB, MB, LB, qbaseB);
        }
        __syncthreads();                             // staged t+1 ready, buf t free
    }

    // reduce l across l4 groups (per slice)
    LA += __shfl_xor(LA, 16); LA += __shfl_xor(LA, 32);
    LB += __shfl_xor(LB, 16); LB += __shfl_xor(LB, 32);

    // disjoint-key merge: slice-1 posts, slice-0 merges + writes
    float* mg = (float*)MEM + p * 2560 + lane * 40;  // 160B/lane, 16B-aligned chunks
    if (s) {
#pragma unroll
        for (int dt = 0; dt < 4; ++dt) *reinterpret_cast<f32x4*>(mg + dt * 4) = OA[dt];
        mg[16] = MA; mg[17] = LA;
#pragma unroll
        for (int dt = 0; dt < 4; ++dt) *reinterpret_cast<f32x4*>(mg + 20 + dt * 4) = OB[dt];
        mg[36] = MB; mg[37] = LB;
    }
    __syncthreads();
    if (!s) {
        {
            float m1 = mg[16], l1 = mg[17];
            float ms = fmaxf(MA, m1);
            float e0 = __expf(MA - ms), e1 = __expf(m1 - ms);
            float inv = 1.0f / (LA * e0 + l1 * e1);
            int tA = qbaseA + l15;
#pragma unroll
            for (int dt = 0; dt < 4; ++dt) {
                f32x4 o1 = *reinterpret_cast<const f32x4*>(mg + dt * 4);
                float4 o;
                o.x = (OA[dt][0] * e0 + o1[0] * e1) * inv;
                o.y = (OA[dt][1] * e0 + o1[1] * e1) * inv;
                o.z = (OA[dt][2] * e0 + o1[2] * e1) * inv;
                o.w = (OA[dt][3] * e0 + o1[3] * e1) * inv;
                *reinterpret_cast<float4*>(outp + (b * 2048 + tA) * 1024 + h * 64 + dt * 16 + l4 * 4) = o;
            }
        }
        {
            float m1 = mg[36], l1 = mg[37];
            float ms = fmaxf(MB, m1);
            float e0 = __expf(MB - ms), e1 = __expf(m1 - ms);
            float inv = 1.0f / (LB * e0 + l1 * e1);
            int tB = qbaseB + l15;
#pragma unroll
            for (int dt = 0; dt < 4; ++dt) {
                f32x4 o1 = *reinterpret_cast<const f32x4*>(mg + 20 + dt * 4);
                float4 o;
                o.x = (OB[dt][0] * e0 + o1[0] * e1) * inv;
                o.y = (OB[dt][1] * e0 + o1[1] * e1) * inv;
                o.z = (OB[dt][2] * e0 + o1[2] * e1) * inv;
                o.w = (OB[dt][3] * e0 + o1[3] * e1) * inv;
                *reinterpret_cast<float4*>(outp + (b * 2048 + tB) * 1024 + h * 64 + dt * 16 + l4 * 4) = o;
            }
        }
    }
}

extern "C" void kernel_launch(void* const* d_in, const int* in_sizes, int n_in,
                              void* d_out, int out_size, void* d_ws, size_t ws_size,
                              hipStream_t stream) {
    const float* hidden = (const float*)d_in[0];
    const float* amask  = (const float*)d_in[1];
    const float* Wq = (const float*)d_in[2];
    const float* bq = (const float*)d_in[3];
    const float* Aq = (const float*)d_in[4];
    const float* Bq = (const float*)d_in[5];
    const float* Wk = (const float*)d_in[6];
    const float* bk = (const float*)d_in[7];
    const float* Wv = (const float*)d_in[8];
    const float* bv = (const float*)d_in[9];
    const float* Av = (const float*)d_in[10];
    const float* Bv = (const float*)d_in[11];
    float* outp = (float*)d_out;

    char* ws = (char*)d_ws;
    short* Xbf = (short*)(ws);                 // 8 MB  [4096][1024] bf16
    short* Wqe = (short*)(ws + (8 << 20));     // 2 MB
    short* Wke = (short*)(ws + (10 << 20));    // 2 MB
    short* Wve = (short*)(ws + (12 << 20));    // 2 MB
    short* Qb  = (short*)(ws + (14 << 20));    // 8 MB  [b][h][t][d]
    short* Kb  = (short*)(ws + (22 << 20));    // 8 MB  [b][h][t][d]
    short* Vtb = (short*)(ws + (30 << 20));    // 8 MB  [b][h][d][t]

    cvt_hidden<<<4096, 256, 0, stream>>>(hidden, Xbf);
    prep_w<<<dim3(4096, 3), 256, 0, stream>>>(Wq, Aq, Bq, Wk, Wv, Av, Bv, Wqe, Wke, Wve);
    proj_gemm<<<dim3(8, 32, 3), 256, 0, stream>>>(Xbf, Wqe, Wke, Wve, bq, bk, bv, Qb, Kb, Vtb);
    attn<<<1024, 256, 0, stream>>>(Qb, Kb, Vtb, amask, outp);
}

// Round 14
// 113.079 us; speedup vs baseline: 1.9106x; 1.0390x over previous
//
#include <hip/hip_runtime.h>
#include <hip/hip_bf16.h>

#define BB 2
#define TT 2048
#define DMM 1024
#define HH 16
#define HDD 64

typedef __attribute__((ext_vector_type(8))) short bf16x8;
typedef __attribute__((ext_vector_type(4))) short short4v;
typedef __attribute__((ext_vector_type(4))) float f32x4;

static __device__ __forceinline__ short f2bf(float f) {
    __hip_bfloat16 h = __float2bfloat16(f);
    return *reinterpret_cast<short*>(&h);
}

static __device__ __forceinline__ void gl_lds16(const void* g, void* l) {
    __builtin_amdgcn_global_load_lds(
        (const __attribute__((address_space(1))) void*)g,
        (__attribute__((address_space(3))) void*)l, 16, 0, 0);
}

// ---- hidden f32 -> bf16 (4 elems/thread) ----
__global__ void cvt_hidden(const float* __restrict__ x, short* __restrict__ y) {
    int i = blockIdx.x * 256 + threadIdx.x;          // 1M threads, 4M elems
    float4 v = reinterpret_cast<const float4*>(x)[i];
    short4v o;
    o[0] = f2bf(v.x); o[1] = f2bf(v.y); o[2] = f2bf(v.z); o[3] = f2bf(v.w);
    reinterpret_cast<short4v*>(y)[i] = o;
}

// ---- W_eff = W + 2.0 * B@A (Q,V) or plain W (K), cast bf16; grid.y = mode ----
__global__ void prep_w(const float* __restrict__ Wq, const float* __restrict__ Aq, const float* __restrict__ Bq,
                       const float* __restrict__ Wk,
                       const float* __restrict__ Wv, const float* __restrict__ Av, const float* __restrict__ Bv,
                       short* __restrict__ Wqe, short* __restrict__ Wke, short* __restrict__ Wve) {
    const int mode = blockIdx.y;
    const float* W = (mode == 0) ? Wq : (mode == 1) ? Wk : Wv;
    const float* A = (mode == 0) ? Aq : Av;
    const float* Bm = (mode == 0) ? Bq : Bv;
    short* outp = (mode == 0) ? Wqe : (mode == 1) ? Wke : Wve;
    int idx = blockIdx.x * 256 + threadIdx.x;        // 1M elems
    int n = idx >> 10, k = idx & 1023;
    float v = W[idx];
    if (mode != 1) {
        float s = 0.f;
#pragma unroll
        for (int r = 0; r < 8; ++r) s += Bm[n * 8 + r] * A[r * 1024 + k];
        v += 2.0f * s;
    }
    outp[idx] = f2bf(v);
}

// ---- projection GEMM (m97-style): global_load_lds staging, swizzled LDS ----
// z = 0: Q (scale 0.125, [b][h][t][d]); z=1: K (same); z=2: V -> [b][h][d][t]
// V store applies the half-swap permutation (t ^ ((d>>3)&1)<<2) consumed by attn's
// transposed V LDS read (rule 21: producer-side permutation matches read-side XOR).
__global__ __launch_bounds__(256) void proj_gemm(
        const short* __restrict__ Xbf,
        const short* __restrict__ Wq, const short* __restrict__ Wk, const short* __restrict__ Wv,
        const float* __restrict__ bq, const float* __restrict__ bk, const float* __restrict__ bv,
        short* __restrict__ Qb, short* __restrict__ Kb, short* __restrict__ Vtb) {
    __shared__ __align__(16) char As[128 * 128];     // 128 rows x 64 bf16 (128B), swizzled
    __shared__ __align__(16) char Bs[128 * 128];

    const int mode = blockIdx.z;
    const short* Wbf = (mode == 0) ? Wq : (mode == 1) ? Wk : Wv;
    const float* bias = (mode == 0) ? bq : (mode == 1) ? bk : bv;
    short* outp = (mode == 0) ? Qb : (mode == 1) ? Kb : Vtb;
    const float scale = (mode == 0) ? 0.125f : 1.0f;  // HD^-0.5 folded into Q

    const int tid = threadIdx.x;
    const int wave = tid >> 6, lane = tid & 63;
    const int l15 = lane & 15, l4 = lane >> 4;
    const int m0 = blockIdx.y * 128, n0 = blockIdx.x * 128;
    const int wm = (wave >> 1) * 64, wn = (wave & 1) * 64;

    const int lrow = lane >> 3;                      // 0..7
    const int lchunk = lane & 7;                     // 16B chunk
    const int srcoff = (lchunk ^ lrow) * 8;          // shorts
    char* ldsA = As + wave * 4096;
    char* ldsB = Bs + wave * 4096;

    const char* P1 = (mode == 2) ? As : Bs;
    const char* P2 = (mode == 2) ? Bs : As;
    const int o1 = (mode == 2) ? wm : wn;
    const int o2 = (mode == 2) ? wn : wm;

    f32x4 acc[4][4] = {};

    for (int k0 = 0; k0 < 1024; k0 += 64) {
        __syncthreads();
#pragma unroll
        for (int i = 0; i < 4; ++i) {
            int row = wave * 32 + i * 8 + lrow;
            gl_lds16(Xbf + (m0 + row) * 1024 + k0 + srcoff, ldsA + i * 1024);
            gl_lds16(Wbf + (n0 + row) * 1024 + k0 + srcoff, ldsB + i * 1024);
        }
        __syncthreads();
#pragma unroll
        for (int kk = 0; kk < 2; ++kk) {
            const int colb = kk * 64 + l4 * 16;
            bf16x8 f1[4], f2[4];
#pragma unroll
            for (int x = 0; x < 4; ++x) {
                int r1 = o1 + x * 16 + l15;
                f1[x] = *reinterpret_cast<const bf16x8*>(P1 + ((r1 * 128 + colb) ^ ((r1 & 7) << 4)));
                int r2 = o2 + x * 16 + l15;
                f2[x] = *reinterpret_cast<const bf16x8*>(P2 + ((r2 * 128 + colb) ^ ((r2 & 7) << 4)));
            }
#pragma unroll
            for (int x = 0; x < 4; ++x)
#pragma unroll
                for (int y = 0; y < 4; ++y)
                    acc[x][y] = __builtin_amdgcn_mfma_f32_16x16x32_bf16(f1[x], f2[y], acc[x][y], 0, 0, 0);
        }
    }

    if (mode != 2) {
#pragma unroll
        for (int x = 0; x < 4; ++x) {
            int gnb = n0 + wn + x * 16 + l4 * 4;
            int hh = gnb >> 6, d = gnb & 63;
            float4 bv4 = *reinterpret_cast<const float4*>(bias + gnb);
#pragma unroll
            for (int y = 0; y < 4; ++y) {
                int gm = m0 + wm + y * 16 + l15;
                int bb = gm >> 11, t = gm & 2047;
                short4v o;
                o[0] = f2bf((acc[x][y][0] + bv4.x) * scale);
                o[1] = f2bf((acc[x][y][1] + bv4.y) * scale);
                o[2] = f2bf((acc[x][y][2] + bv4.z) * scale);
                o[3] = f2bf((acc[x][y][3] + bv4.w) * scale);
                *reinterpret_cast<short4v*>(outp + ((bb * 16 + hh) * 2048 + t) * 64 + d) = o;
            }
        }
    } else {
#pragma unroll
        for (int x = 0; x < 4; ++x) {
            int gmb = m0 + wm + x * 16 + l4 * 4;
            int bb = gmb >> 11, t = gmb & 2047;
#pragma unroll
            for (int y = 0; y < 4; ++y) {
                int gn = n0 + wn + y * 16 + l15;
                int hh = gn >> 6, d = gn & 63;
                int tx = ((gn >> 3) & 1) << 2;       // half-swap for attn V read
                float bvs = bias[gn];
                short4v o;
                o[0] = f2bf(acc[x][y][0] + bvs);
                o[1] = f2bf(acc[x][y][1] + bvs);
                o[2] = f2bf(acc[x][y][2] + bvs);
                o[3] = f2bf(acc[x][y][3] + bvs);
                *reinterpret_cast<short4v*>(outp + ((bb * 16 + hh) * 64 + d) * 2048 + (t ^ tx)) = o;
            }
        }
    }
}

// ---- flash attention v9: key-slice split, transposed V LDS, bit-mixed j ----
// 1024 blocks x 4 waves. Block (xcd,k): bh = xcd*4 + ((k>>2)&3),
// j = ((k>>5)<<3)|((k&3)<<1)|((k>>4)&1)  -> each CU's blocks mix j (load balance).
// Wave (p = wv&1, s = wv>>1): pair i=2j+p, key-slice s.
// V LDS layout [key-chunk c][d]: wave wv stages chunk wv across all 64 d.
// V read b64 with h = (l4&1)^(l15>>3) (matches proj's half-swap) -> 2-way, free.

#define STAGE(BUF, T) do {                                                           \
    const int _kv = (T) << 5;                                                        \
    gl_lds16(Kp + (_kv + krow) * 64 + kswz, MEM + (BUF) * 4096 + wv * 1024);         \
    gl_lds16(Vp + lane * 2048 + _kv + wv * 8, MEM + 8192 + (BUF) * 4096 + wv * 1024);\
} while (0)

#define SLICEJOB(QF0, QF1, OO, M, L, QBASE) do {                                     \
    f32x4 ss = {};                                                                   \
    ss = __builtin_amdgcn_mfma_f32_16x16x32_bf16(kf0, QF0, ss, 0, 0, 0);             \
    ss = __builtin_amdgcn_mfma_f32_16x16x32_bf16(kf1, QF1, ss, 0, 0, 0);             \
    float pr[4];                                                                     \
    if (kvs + 15 > (QBASE)) {                                                        \
        _Pragma("unroll")                                                            \
        for (int r = 0; r < 4; ++r) {                                                \
            float v = ss[r] + mv[r];                                                 \
            if (kvs + l4*4 + r > (QBASE) + l15) v = -1e30f;                          \
            pr[r] = v;                                                               \
        }                                                                            \
    } else {                                                                         \
        _Pragma("unroll")                                                            \
        for (int r = 0; r < 4; ++r) pr[r] = ss[r] + mv[r];                           \
    }                                                                                \
    float tl = fmaxf(fmaxf(pr[0], pr[1]), fmaxf(pr[2], pr[3]));                      \
    if (!__all(tl - (M) <= 8.0f)) {                                                  \
        float tm = tl;                                                               \
        tm = fmaxf(tm, __shfl_xor(tm, 16));                                          \
        tm = fmaxf(tm, __shfl_xor(tm, 32));                                          \
        float mn = fmaxf((M), tm);                                                   \
        float al = __expf((M) - mn);                                                 \
        M = mn; L *= al;                                                             \
        _Pragma("unroll")                                                            \
        for (int dt = 0; dt < 4; ++dt)                                               \
            _Pragma("unroll")                                                        \
            for (int r = 0; r < 4; ++r) OO[dt][r] *= al;                             \
    }                                                                                \
    _Pragma("unroll")                                                                \
    for (int r = 0; r < 4; ++r) pr[r] = __expf(pr[r] - (M));                         \
    L += (pr[0] + pr[1]) + (pr[2] + pr[3]);                                          \
    short4v pa;                                                                      \
    _Pragma("unroll")                                                                \
    for (int r = 0; r < 4; ++r) pa[r] = f2bf(pr[r]);                                 \
    _Pragma("unroll")                                                                \
    for (int dt = 0; dt < 4; ++dt)                                                   \
        OO[dt] = __builtin_amdgcn_mfma_f32_16x16x16bf16_1k(vf[dt], pa, OO[dt], 0, 0, 0); \
} while (0)

// LDS (bytes): K dbuf [2][4096] @0 | V dbuf [2][4096] @8192 | mask 8192 @16384 = 24576
// merge regions reuse @0 after the stream loop (2 pairs x 64 lanes x 160B = 20480)
__global__ __launch_bounds__(256, 4) void attn(
        const short* __restrict__ Qb, const short* __restrict__ Kb,
        const short* __restrict__ Vt, const float* __restrict__ amask,
        float* __restrict__ outp) {
    __shared__ __align__(16) char MEM[24576];

    const int tid = threadIdx.x, wv = tid >> 6, lane = tid & 63;
    const int l15 = lane & 15, l4 = lane >> 4;
    // XCD-chunked + bit-mixed j: robust CU-level balance under round-robin fill
    const int xcd = blockIdx.x & 7;
    const int k   = blockIdx.x >> 3;                 // 0..127 within XCD
    const int j   = ((k >> 5) << 3) | ((k & 3) << 1) | ((k >> 4) & 1);  // 0..31
    const int bh  = xcd * 4 + ((k >> 2) & 3);        // 4 bh per XCD (L2 locality)
    const int p  = wv & 1;                           // pair in block
    const int s  = wv >> 1;                          // key-slice
    const int i  = 2 * j + p;                        // pair index 0..63
    const int b = bh >> 4, h = bh & 15;

    const short* Qp = Qb + bh * TT * HDD;
    const short* Kp = Kb + bh * TT * HDD;
    const short* Vp = Vt + bh * HDD * TT;
    const float* mp = amask + b * TT;
    float* mlds = (float*)(MEM + 16384);

    const int qbaseA = (127 - i) << 4;
    const int qbaseB = i << 4;
    const int nkA = ((qbaseA + 15 - 16 * s) >> 5) + 1;   // slice-aware causal bounds
    const int nkB = ((qbaseB + 15 - 16 * s) >> 5) + 1;   // (0 when slice fully masked)
    const int NT = ((127 - 2 * j) * 16 + 47) >> 5;       // block stream extent

    // staging lane geometry: K rows [wv*8,+8) pre-swizzled; V chunk wv, d=lane
    const int krow = wv * 8 + (lane >> 3);
    const int kswz = ((lane & 7) ^ (lane >> 3)) * 8;     // shorts

    // LDS read offsets (bytes)
    const int kb0 = (16 * s + l15) * 128 + ((l4 ^ (l15 & 7)) << 4);
    const int vb0 = (2 * s + (l4 >> 1)) * 1024 + l15 * 16 + (((l4 & 1) ^ (l15 >> 3)) << 3);

    // prologue: mask -> LDS (whole row for this b)
    {
        int mi8 = tid * 8;
        float4 a = *reinterpret_cast<const float4*>(mp + mi8);
        float4 c = *reinterpret_cast<const float4*>(mp + mi8 + 4);
        *reinterpret_cast<float4*>(mlds + mi8) = a;
        *reinterpret_cast<float4*>(mlds + mi8 + 4) = c;
    }

    bf16x8 qfA0 = *reinterpret_cast<const bf16x8*>(Qp + (qbaseA + l15) * 64 + l4 * 8);
    bf16x8 qfA1 = *reinterpret_cast<const bf16x8*>(Qp + (qbaseA + l15) * 64 + 32 + l4 * 8);
    bf16x8 qfB0 = *reinterpret_cast<const bf16x8*>(Qp + (qbaseB + l15) * 64 + l4 * 8);
    bf16x8 qfB1 = *reinterpret_cast<const bf16x8*>(Qp + (qbaseB + l15) * 64 + 32 + l4 * 8);

    f32x4 OA[4] = {}, OB[4] = {};
    float MA = -1e30f, LA = 0.f, MB = -1e30f, LB = 0.f;

    STAGE(0, 0);
    __syncthreads();                                 // staging + mask drained

    for (int t = 0; t < NT; ++t) {
        const int cur = t & 1;
        if (t + 1 < NT) STAGE(cur ^ 1, t + 1);       // async, lands by next barrier
        if (t < nkA) {
            const char* Kcur = MEM + cur * 4096;
            const char* Vcur = MEM + 8192 + cur * 4096;
            bf16x8 kf0 = *reinterpret_cast<const bf16x8*>(Kcur + kb0);
            bf16x8 kf1 = *reinterpret_cast<const bf16x8*>(Kcur + (kb0 ^ 64));
            short4v vf[4];
#pragma unroll
            for (int dt = 0; dt < 4; ++dt)
                vf[dt] = *reinterpret_cast<const short4v*>(Vcur + vb0 + dt * 256);
            const int kvs = (t << 5) + 16 * s;
            float4 mv = *reinterpret_cast<const float4*>(mlds + kvs + l4 * 4);
            SLICEJOB(qfA0, qfA1, OA, MA, LA, qbaseA);
            if (t < nkB) SLICEJOB(qfB0, qfB1, OB, MB, LB, qbaseB);
        }
        __syncthreads();                             // staged t+1 ready, buf t free
    }

    // reduce l across l4 groups (per slice)
    LA += __shfl_xor(LA, 16); LA += __shfl_xor(LA, 32);
    LB += __shfl_xor(LB, 16); LB += __shfl_xor(LB, 32);

    // disjoint-key merge: slice-1 posts, slice-0 merges + writes
    float* mg = (float*)MEM + p * 2560 + lane * 40;  // 160B/lane, 16B-aligned chunks
    if (s) {
#pragma unroll
        for (int dt = 0; dt < 4; ++dt) *reinterpret_cast<f32x4*>(mg + dt * 4) = OA[dt];
        mg[16] = MA; mg[17] = LA;
#pragma unroll
        for (int dt = 0; dt < 4; ++dt) *reinterpret_cast<f32x4*>(mg + 20 + dt * 4) = OB[dt];
        mg[36] = MB; mg[37] = LB;
    }
    __syncthreads();
    if (!s) {
        {
            float m1 = mg[16], l1 = mg[17];
            float ms = fmaxf(MA, m1);
            float e0 = __expf(MA - ms), e1 = __expf(m1 - ms);
            float inv = 1.0f / (LA * e0 + l1 * e1);
            int tA = qbaseA + l15;
#pragma unroll
            for (int dt = 0; dt < 4; ++dt) {
                f32x4 o1 = *reinterpret_cast<const f32x4*>(mg + dt * 4);
                float4 o;
                o.x = (OA[dt][0] * e0 + o1[0] * e1) * inv;
                o.y = (OA[dt][1] * e0 + o1[1] * e1) * inv;
                o.z = (OA[dt][2] * e0 + o1[2] * e1) * inv;
                o.w = (OA[dt][3] * e0 + o1[3] * e1) * inv;
                *reinterpret_cast<float4*>(outp + (b * 2048 + tA) * 1024 + h * 64 + dt * 16 + l4 * 4) = o;
            }
        }
        {
            float m1 = mg[36], l1 = mg[37];
            float ms = fmaxf(MB, m1);
            float e0 = __expf(MB - ms), e1 = __expf(m1 - ms);
            float inv = 1.0f / (LB * e0 + l1 * e1);
            int tB = qbaseB + l15;
#pragma unroll
            for (int dt = 0; dt < 4; ++dt) {
                f32x4 o1 = *reinterpret_cast<const f32x4*>(mg + 20 + dt * 4);
                float4 o;
                o.x = (OB[dt][0] * e0 + o1[0] * e1) * inv;
                o.y = (OB[dt][1] * e0 + o1[1] * e1) * inv;
                o.z = (OB[dt][2] * e0 + o1[2] * e1) * inv;
                o.w = (OB[dt][3] * e0 + o1[3] * e1) * inv;
                *reinterpret_cast<float4*>(outp + (b * 2048 + tB) * 1024 + h * 64 + dt * 16 + l4 * 4) = o;
            }
        }
    }
}

extern "C" void kernel_launch(void* const* d_in, const int* in_sizes, int n_in,
                              void* d_out, int out_size, void* d_ws, size_t ws_size,
                              hipStream_t stream) {
    const float* hidden = (const float*)d_in[0];
    const float* amask  = (const float*)d_in[1];
    const float* Wq = (const float*)d_in[2];
    const float* bq = (const float*)d_in[3];
    const float* Aq = (const float*)d_in[4];
    const float* Bq = (const float*)d_in[5];
    const float* Wk = (const float*)d_in[6];
    const float* bk = (const float*)d_in[7];
    const float* Wv = (const float*)d_in[8];
    const float* bv = (const float*)d_in[9];
    const float* Av = (const float*)d_in[10];
    const float* Bv = (const float*)d_in[11];
    float* outp = (float*)d_out;

    char* ws = (char*)d_ws;
    short* Xbf = (short*)(ws);                 // 8 MB  [4096][1024] bf16
    short* Wqe = (short*)(ws + (8 << 20));     // 2 MB
    short* Wke = (short*)(ws + (10 << 20));    // 2 MB
    short* Wve = (short*)(ws + (12 << 20));    // 2 MB
    short* Qb  = (short*)(ws + (14 << 20));    // 8 MB  [b][h][t][d]
    short* Kb  = (short*)(ws + (22 << 20));    // 8 MB  [b][h][t][d]
    short* Vtb = (short*)(ws + (30 << 20));    // 8 MB  [b][h][d][t] (half-swapped)

    cvt_hidden<<<4096, 256, 0, stream>>>(hidden, Xbf);
    prep_w<<<dim3(4096, 3), 256, 0, stream>>>(Wq, Aq, Bq, Wk, Wv, Av, Bv, Wqe, Wke, Wve);
    proj_gemm<<<dim3(8, 32, 3), 256, 0, stream>>>(Xbf, Wqe, Wke, Wve, bq, bk, bv, Qb, Kb, Vtb);
    attn<<<1024, 256, 0, stream>>>(Qb, Kb, Vtb, amask, outp);
}

// Round 16
// 109.655 us; speedup vs baseline: 1.9702x; 1.0312x over previous
//
#include <hip/hip_runtime.h>
#include <hip/hip_bf16.h>

#define BB 2
#define TT 2048
#define DMM 1024
#define HH 16
#define HDD 64

typedef __attribute__((ext_vector_type(8))) short bf16x8;
typedef __attribute__((ext_vector_type(4))) short short4v;
typedef __attribute__((ext_vector_type(4))) float f32x4;

static __device__ __forceinline__ short f2bf(float f) {
    __hip_bfloat16 h = __float2bfloat16(f);
    return *reinterpret_cast<short*>(&h);
}

static __device__ __forceinline__ void gl_lds16(const void* g, void* l) {
    __builtin_amdgcn_global_load_lds(
        (const __attribute__((address_space(1))) void*)g,
        (__attribute__((address_space(3))) void*)l, 16, 0, 0);
}

// ---- hidden f32 -> bf16 (4 elems/thread) ----
__global__ void cvt_hidden(const float* __restrict__ x, short* __restrict__ y) {
    int i = blockIdx.x * 256 + threadIdx.x;          // 1M threads, 4M elems
    float4 v = reinterpret_cast<const float4*>(x)[i];
    short4v o;
    o[0] = f2bf(v.x); o[1] = f2bf(v.y); o[2] = f2bf(v.z); o[3] = f2bf(v.w);
    reinterpret_cast<short4v*>(y)[i] = o;
}

// ---- W_eff = W + 2.0 * B@A (Q,V) or plain W (K), cast bf16; grid.y = mode ----
__global__ void prep_w(const float* __restrict__ Wq, const float* __restrict__ Aq, const float* __restrict__ Bq,
                       const float* __restrict__ Wk,
                       const float* __restrict__ Wv, const float* __restrict__ Av, const float* __restrict__ Bv,
                       short* __restrict__ Wqe, short* __restrict__ Wke, short* __restrict__ Wve) {
    const int mode = blockIdx.y;
    const float* W = (mode == 0) ? Wq : (mode == 1) ? Wk : Wv;
    const float* A = (mode == 0) ? Aq : Av;
    const float* Bm = (mode == 0) ? Bq : Bv;
    short* outp = (mode == 0) ? Wqe : (mode == 1) ? Wke : Wve;
    int idx = blockIdx.x * 256 + threadIdx.x;        // 1M elems
    int n = idx >> 10, k = idx & 1023;
    float v = W[idx];
    if (mode != 1) {
        float s = 0.f;
#pragma unroll
        for (int r = 0; r < 8; ++r) s += Bm[n * 8 + r] * A[r * 1024 + k];
        v += 2.0f * s;
    }
    outp[idx] = f2bf(v);
}

// ---- projection GEMM (m97-style): global_load_lds staging, swizzled LDS ----
// z = 0: Q (scale 0.125, [b][h][t][d]); z=1: K (same); z=2: V -> [b][h][d][t]
// V store applies the half-swap permutation (t ^ ((d>>3)&1)<<2) consumed by attn's
// transposed V LDS read (rule 21: producer-side permutation matches read-side XOR).
__global__ __launch_bounds__(256) void proj_gemm(
        const short* __restrict__ Xbf,
        const short* __restrict__ Wq, const short* __restrict__ Wk, const short* __restrict__ Wv,
        const float* __restrict__ bq, const float* __restrict__ bk, const float* __restrict__ bv,
        short* __restrict__ Qb, short* __restrict__ Kb, short* __restrict__ Vtb) {
    __shared__ __align__(16) char As[128 * 128];     // 128 rows x 64 bf16 (128B), swizzled
    __shared__ __align__(16) char Bs[128 * 128];

    const int mode = blockIdx.z;
    const short* Wbf = (mode == 0) ? Wq : (mode == 1) ? Wk : Wv;
    const float* bias = (mode == 0) ? bq : (mode == 1) ? bk : bv;
    short* outp = (mode == 0) ? Qb : (mode == 1) ? Kb : Vtb;
    const float scale = (mode == 0) ? 0.125f : 1.0f;  // HD^-0.5 folded into Q

    const int tid = threadIdx.x;
    const int wave = tid >> 6, lane = tid & 63;
    const int l15 = lane & 15, l4 = lane >> 4;
    const int m0 = blockIdx.y * 128, n0 = blockIdx.x * 128;
    const int wm = (wave >> 1) * 64, wn = (wave & 1) * 64;

    const int lrow = lane >> 3;                      // 0..7
    const int lchunk = lane & 7;                     // 16B chunk
    const int srcoff = (lchunk ^ lrow) * 8;          // shorts
    char* ldsA = As + wave * 4096;
    char* ldsB = Bs + wave * 4096;

    const char* P1 = (mode == 2) ? As : Bs;
    const char* P2 = (mode == 2) ? Bs : As;
    const int o1 = (mode == 2) ? wm : wn;
    const int o2 = (mode == 2) ? wn : wm;

    f32x4 acc[4][4] = {};

    for (int k0 = 0; k0 < 1024; k0 += 64) {
        __syncthreads();
#pragma unroll
        for (int i = 0; i < 4; ++i) {
            int row = wave * 32 + i * 8 + lrow;
            gl_lds16(Xbf + (m0 + row) * 1024 + k0 + srcoff, ldsA + i * 1024);
            gl_lds16(Wbf + (n0 + row) * 1024 + k0 + srcoff, ldsB + i * 1024);
        }
        __syncthreads();
#pragma unroll
        for (int kk = 0; kk < 2; ++kk) {
            const int colb = kk * 64 + l4 * 16;
            bf16x8 f1[4], f2[4];
#pragma unroll
            for (int x = 0; x < 4; ++x) {
                int r1 = o1 + x * 16 + l15;
                f1[x] = *reinterpret_cast<const bf16x8*>(P1 + ((r1 * 128 + colb) ^ ((r1 & 7) << 4)));
                int r2 = o2 + x * 16 + l15;
                f2[x] = *reinterpret_cast<const bf16x8*>(P2 + ((r2 * 128 + colb) ^ ((r2 & 7) << 4)));
            }
#pragma unroll
            for (int x = 0; x < 4; ++x)
#pragma unroll
                for (int y = 0; y < 4; ++y)
                    acc[x][y] = __builtin_amdgcn_mfma_f32_16x16x32_bf16(f1[x], f2[y], acc[x][y], 0, 0, 0);
        }
    }

    if (mode != 2) {
#pragma unroll
        for (int x = 0; x < 4; ++x) {
            int gnb = n0 + wn + x * 16 + l4 * 4;
            int hh = gnb >> 6, d = gnb & 63;
            float4 bv4 = *reinterpret_cast<const float4*>(bias + gnb);
#pragma unroll
            for (int y = 0; y < 4; ++y) {
                int gm = m0 + wm + y * 16 + l15;
                int bb = gm >> 11, t = gm & 2047;
                short4v o;
                o[0] = f2bf((acc[x][y][0] + bv4.x) * scale);
                o[1] = f2bf((acc[x][y][1] + bv4.y) * scale);
                o[2] = f2bf((acc[x][y][2] + bv4.z) * scale);
                o[3] = f2bf((acc[x][y][3] + bv4.w) * scale);
                *reinterpret_cast<short4v*>(outp + ((bb * 16 + hh) * 2048 + t) * 64 + d) = o;
            }
        }
    } else {
#pragma unroll
        for (int x = 0; x < 4; ++x) {
            int gmb = m0 + wm + x * 16 + l4 * 4;
            int bb = gmb >> 11, t = gmb & 2047;
#pragma unroll
            for (int y = 0; y < 4; ++y) {
                int gn = n0 + wn + y * 16 + l15;
                int hh = gn >> 6, d = gn & 63;
                int tx = ((gn >> 3) & 1) << 2;       // half-swap for attn V read
                float bvs = bias[gn];
                short4v o;
                o[0] = f2bf(acc[x][y][0] + bvs);
                o[1] = f2bf(acc[x][y][1] + bvs);
                o[2] = f2bf(acc[x][y][2] + bvs);
                o[3] = f2bf(acc[x][y][3] + bvs);
                *reinterpret_cast<short4v*>(outp + ((bb * 16 + hh) * 64 + d) * 2048 + (t ^ tx)) = o;
            }
        }
    }
}

// ---- flash attention v10: counted-vmcnt pipeline, 4-buffer rotation ----
// Same decomposition as v9 (key-slice split, transposed V LDS, bit-mixed j).
// Stream loop uses RAW s_barrier + counted vmcnt (never vmcnt(0) mid-loop):
// staging loads stay in flight across barriers; 4-deep buffer rotation makes
// the overwrite distance 3 iterations -> provably race-free with one barrier
// per iteration (STAGE(t+2) clobbers buf[(t-2)%4]; all readers of it finished
// before barrier(t-1), which precedes the staging issue in program order).

#define STAGE(BUF, T) do {                                                           \
    const int _kv = (T) << 5;                                                        \
    gl_lds16(Kp + (_kv + krow) * 64 + kswz, MEM + (BUF) * 4096 + wv * 1024);         \
    gl_lds16(Vp + lane * 2048 + _kv + wv * 8, MEM + 16384 + (BUF) * 4096 + wv * 1024);\
} while (0)

#define SLICEJOB(QF0, QF1, OO, M, L, QBASE) do {                                     \
    f32x4 ss = {};                                                                   \
    ss = __builtin_amdgcn_mfma_f32_16x16x32_bf16(kf0, QF0, ss, 0, 0, 0);             \
    ss = __builtin_amdgcn_mfma_f32_16x16x32_bf16(kf1, QF1, ss, 0, 0, 0);             \
    float pr[4];                                                                     \
    if (kvs + 15 > (QBASE)) {                                                        \
        _Pragma("unroll")                                                            \
        for (int r = 0; r < 4; ++r) {                                                \
            float v = ss[r] + mv[r];                                                 \
            if (kvs + l4*4 + r > (QBASE) + l15) v = -1e30f;                          \
            pr[r] = v;                                                               \
        }                                                                            \
    } else {                                                                         \
        _Pragma("unroll")                                                            \
        for (int r = 0; r < 4; ++r) pr[r] = ss[r] + mv[r];                           \
    }                                                                                \
    float tl = fmaxf(fmaxf(pr[0], pr[1]), fmaxf(pr[2], pr[3]));                      \
    if (!__all(tl - (M) <= 8.0f)) {                                                  \
        float tm = tl;                                                               \
        tm = fmaxf(tm, __shfl_xor(tm, 16));                                          \
        tm = fmaxf(tm, __shfl_xor(tm, 32));                                          \
        float mn = fmaxf((M), tm);                                                   \
        float al = __expf((M) - mn);                                                 \
        M = mn; L *= al;                                                             \
        _Pragma("unroll")                                                            \
        for (int dt = 0; dt < 4; ++dt)                                               \
            _Pragma("unroll")                                                        \
            for (int r = 0; r < 4; ++r) OO[dt][r] *= al;                             \
    }                                                                                \
    _Pragma("unroll")                                                                \
    for (int r = 0; r < 4; ++r) pr[r] = __expf(pr[r] - (M));                         \
    L += (pr[0] + pr[1]) + (pr[2] + pr[3]);                                          \
    short4v pa;                                                                      \
    _Pragma("unroll")                                                                \
    for (int r = 0; r < 4; ++r) pa[r] = f2bf(pr[r]);                                 \
    _Pragma("unroll")                                                                \
    for (int dt = 0; dt < 4; ++dt)                                                   \
        OO[dt] = __builtin_amdgcn_mfma_f32_16x16x16bf16_1k(vf[dt], pa, OO[dt], 0, 0, 0); \
} while (0)

// LDS (bytes): K 4-buf [4][4096] @0 | V 4-buf [4][4096] @16384 | mask 8192 @32768 = 40960
// merge regions reuse @0 after the stream loop (20480 B, over dead K/V buffers)
__global__ __launch_bounds__(256, 4) void attn(
        const short* __restrict__ Qb, const short* __restrict__ Kb,
        const short* __restrict__ Vt, const float* __restrict__ amask,
        float* __restrict__ outp) {
    __shared__ __align__(16) char MEM[40960];

    const int tid = threadIdx.x, wv = tid >> 6, lane = tid & 63;
    const int l15 = lane & 15, l4 = lane >> 4;
    // XCD-chunked + bit-mixed j: robust CU-level balance under round-robin fill
    const int xcd = blockIdx.x & 7;
    const int k   = blockIdx.x >> 3;                 // 0..127 within XCD
    const int j   = ((k >> 5) << 3) | ((k & 3) << 1) | ((k >> 4) & 1);  // 0..31
    const int bh  = xcd * 4 + ((k >> 2) & 3);        // 4 bh per XCD (L2 locality)
    const int p  = wv & 1;                           // pair in block
    const int s  = wv >> 1;                          // key-slice
    const int i  = 2 * j + p;                        // pair index 0..63
    const int b = bh >> 4, h = bh & 15;

    const short* Qp = Qb + bh * TT * HDD;
    const short* Kp = Kb + bh * TT * HDD;
    const short* Vp = Vt + bh * HDD * TT;
    const float* mp = amask + b * TT;
    float* mlds = (float*)(MEM + 32768);

    const int qbaseA = (127 - i) << 4;
    const int qbaseB = i << 4;
    const int nkA = ((qbaseA + 15 - 16 * s) >> 5) + 1;   // slice-aware causal bounds
    const int nkB = ((qbaseB + 15 - 16 * s) >> 5) + 1;   // (0 when slice fully masked)
    const int NT = ((127 - 2 * j) * 16 + 47) >> 5;       // block stream extent (>= 33)

    // staging lane geometry: K rows [wv*8,+8) pre-swizzled; V chunk wv, d=lane
    const int krow = wv * 8 + (lane >> 3);
    const int kswz = ((lane & 7) ^ (lane >> 3)) * 8;     // shorts

    // LDS read offsets (bytes)
    const int kb0 = (16 * s + l15) * 128 + ((l4 ^ (l15 & 7)) << 4);
    const int vb0 = (2 * s + (l4 >> 1)) * 1024 + l15 * 16 + (((l4 & 1) ^ (l15 >> 3)) << 3);

    // prologue: mask -> LDS (whole row for this b)
    {
        int mi8 = tid * 8;
        float4 a = *reinterpret_cast<const float4*>(mp + mi8);
        float4 c = *reinterpret_cast<const float4*>(mp + mi8 + 4);
        *reinterpret_cast<float4*>(mlds + mi8) = a;
        *reinterpret_cast<float4*>(mlds + mi8 + 4) = c;
    }

    bf16x8 qfA0 = *reinterpret_cast<const bf16x8*>(Qp + (qbaseA + l15) * 64 + l4 * 8);
    bf16x8 qfA1 = *reinterpret_cast<const bf16x8*>(Qp + (qbaseA + l15) * 64 + 32 + l4 * 8);
    bf16x8 qfB0 = *reinterpret_cast<const bf16x8*>(Qp + (qbaseB + l15) * 64 + l4 * 8);
    bf16x8 qfB1 = *reinterpret_cast<const bf16x8*>(Qp + (qbaseB + l15) * 64 + 32 + l4 * 8);

    f32x4 OA[4] = {}, OB[4] = {};
    float MA = -1e30f, LA = 0.f, MB = -1e30f, LB = 0.f;

    STAGE(0, 0);                                     // tiles 0,1 in flight
    STAGE(1, 1);                                     // (NT >= 33, both exist)
    asm volatile("s_waitcnt lgkmcnt(0)" ::: "memory");   // mask writes retired

    int cur = 0;                                     // t % 4
    for (int t = 0; t < NT; ++t) {
        if (t + 2 < NT) {
            int nb = cur + 2; if (nb >= 4) nb -= 4;
            STAGE(nb, t + 2);                        // in flight: t, t+1, t+2
            asm volatile("s_waitcnt vmcnt(4)" ::: "memory");   // tile t landed
        } else if (t + 1 < NT) {
            asm volatile("s_waitcnt vmcnt(2)" ::: "memory");
        } else {
            asm volatile("s_waitcnt vmcnt(0)" ::: "memory");
        }
        asm volatile("s_barrier" ::: "memory");      // tile-t visible to all waves
        if (t < nkA) {
            const char* Kcur = MEM + cur * 4096;
            const char* Vcur = MEM + 16384 + cur * 4096;
            bf16x8 kf0 = *reinterpret_cast<const bf16x8*>(Kcur + kb0);
            bf16x8 kf1 = *reinterpret_cast<const bf16x8*>(Kcur + (kb0 ^ 64));
            short4v vf[4];
#pragma unroll
            for (int dt = 0; dt < 4; ++dt)
                vf[dt] = *reinterpret_cast<const short4v*>(Vcur + vb0 + dt * 256);
            const int kvs = (t << 5) + 16 * s;
            float4 mv = *reinterpret_cast<const float4*>(mlds + kvs + l4 * 4);
            SLICEJOB(qfA0, qfA1, OA, MA, LA, qbaseA);
            if (t < nkB) SLICEJOB(qfB0, qfB1, OB, MB, LB, qbaseB);
        }
        ++cur; if (cur == 4) cur = 0;
    }
    asm volatile("s_barrier" ::: "memory");          // loop reads done before merge reuse

    // reduce l across l4 groups (per slice)
    LA += __shfl_xor(LA, 16); LA += __shfl_xor(LA, 32);
    LB += __shfl_xor(LB, 16); LB += __shfl_xor(LB, 32);

    // disjoint-key merge: slice-1 posts, slice-0 merges + writes
    float* mg = (float*)MEM + p * 2560 + lane * 40;  // 160B/lane, 16B-aligned chunks
    if (s) {
#pragma unroll
        for (int dt = 0; dt < 4; ++dt) *reinterpret_cast<f32x4*>(mg + dt * 4) = OA[dt];
        mg[16] = MA; mg[17] = LA;
#pragma unroll
        for (int dt = 0; dt < 4; ++dt) *reinterpret_cast<f32x4*>(mg + 20 + dt * 4) = OB[dt];
        mg[36] = MB; mg[37] = LB;
    }
    __syncthreads();
    if (!s) {
        {
            float m1 = mg[16], l1 = mg[17];
            float ms = fmaxf(MA, m1);
            float e0 = __expf(MA - ms), e1 = __expf(m1 - ms);
            float inv = 1.0f / (LA * e0 + l1 * e1);
            int tA = qbaseA + l15;
#pragma unroll
            for (int dt = 0; dt < 4; ++dt) {
                f32x4 o1 = *reinterpret_cast<const f32x4*>(mg + dt * 4);
                float4 o;
                o.x = (OA[dt][0] * e0 + o1[0] * e1) * inv;
                o.y = (OA[dt][1] * e0 + o1[1] * e1) * inv;
                o.z = (OA[dt][2] * e0 + o1[2] * e1) * inv;
                o.w = (OA[dt][3] * e0 + o1[3] * e1) * inv;
                *reinterpret_cast<float4*>(outp + (b * 2048 + tA) * 1024 + h * 64 + dt * 16 + l4 * 4) = o;
            }
        }
        {
            float m1 = mg[36], l1 = mg[37];
            float ms = fmaxf(MB, m1);
            float e0 = __expf(MB - ms), e1 = __expf(m1 - ms);
            float inv = 1.0f / (LB * e0 + l1 * e1);
            int tB = qbaseB + l15;
#pragma unroll
            for (int dt = 0; dt < 4; ++dt) {
                f32x4 o1 = *reinterpret_cast<const f32x4*>(mg + 20 + dt * 4);
                float4 o;
                o.x = (OB[dt][0] * e0 + o1[0] * e1) * inv;
                o.y = (OB[dt][1] * e0 + o1[1] * e1) * inv;
                o.z = (OB[dt][2] * e0 + o1[2] * e1) * inv;
                o.w = (OB[dt][3] * e0 + o1[3] * e1) * inv;
                *reinterpret_cast<float4*>(outp + (b * 2048 + tB) * 1024 + h * 64 + dt * 16 + l4 * 4) = o;
            }
        }
    }
}

extern "C" void kernel_launch(void* const* d_in, const int* in_sizes, int n_in,
                              void* d_out, int out_size, void* d_ws, size_t ws_size,
                              hipStream_t stream) {
    const float* hidden = (const float*)d_in[0];
    const float* amask  = (const float*)d_in[1];
    const float* Wq = (const float*)d_in[2];
    const float* bq = (const float*)d_in[3];
    const float* Aq = (const float*)d_in[4];
    const float* Bq = (const float*)d_in[5];
    const float* Wk = (const float*)d_in[6];
    const float* bk = (const float*)d_in[7];
    const float* Wv = (const float*)d_in[8];
    const float* bv = (const float*)d_in[9];
    const float* Av = (const float*)d_in[10];
    const float* Bv = (const float*)d_in[11];
    float* outp = (float*)d_out;

    char* ws = (char*)d_ws;
    short* Xbf = (short*)(ws);                 // 8 MB  [4096][1024] bf16
    short* Wqe = (short*)(ws + (8 << 20));     // 2 MB
    short* Wke = (short*)(ws + (10 << 20));    // 2 MB
    short* Wve = (short*)(ws + (12 << 20));    // 2 MB
    short* Qb  = (short*)(ws + (14 << 20));    // 8 MB  [b][h][t][d]
    short* Kb  = (short*)(ws + (22 << 20));    // 8 MB  [b][h][t][d]
    short* Vtb = (short*)(ws + (30 << 20));    // 8 MB  [b][h][d][t] (half-swapped)

    cvt_hidden<<<4096, 256, 0, stream>>>(hidden, Xbf);
    prep_w<<<dim3(4096, 3), 256, 0, stream>>>(Wq, Aq, Bq, Wk, Wv, Av, Bv, Wqe, Wke, Wve);
    proj_gemm<<<dim3(8, 32, 3), 256, 0, stream>>>(Xbf, Wqe, Wke, Wve, bq, bk, bv, Qb, Kb, Vtb);
    attn<<<1024, 256, 0, stream>>>(Qb, Kb, Vtb, amask, outp);
}

// Round 17
// 108.575 us; speedup vs baseline: 1.9898x; 1.0100x over previous
//
#include <hip/hip_runtime.h>
#include <hip/hip_bf16.h>

#define BB 2
#define TT 2048
#define DMM 1024
#define HH 16
#define HDD 64

typedef __attribute__((ext_vector_type(8))) short bf16x8;
typedef __attribute__((ext_vector_type(4))) short short4v;
typedef __attribute__((ext_vector_type(4))) float f32x4;

static __device__ __forceinline__ short f2bf(float f) {
    __hip_bfloat16 h = __float2bfloat16(f);
    return *reinterpret_cast<short*>(&h);
}

static __device__ __forceinline__ void gl_lds16(const void* g, void* l) {
    __builtin_amdgcn_global_load_lds(
        (const __attribute__((address_space(1))) void*)g,
        (__attribute__((address_space(3))) void*)l, 16, 0, 0);
}

// ---- hidden f32 -> bf16 (4 elems/thread) ----
__global__ void cvt_hidden(const float* __restrict__ x, short* __restrict__ y) {
    int i = blockIdx.x * 256 + threadIdx.x;          // 1M threads, 4M elems
    float4 v = reinterpret_cast<const float4*>(x)[i];
    short4v o;
    o[0] = f2bf(v.x); o[1] = f2bf(v.y); o[2] = f2bf(v.z); o[3] = f2bf(v.w);
    reinterpret_cast<short4v*>(y)[i] = o;
}

// ---- W_eff = W + 2.0 * B@A (Q,V) or plain W (K), cast bf16; grid.y = mode ----
__global__ void prep_w(const float* __restrict__ Wq, const float* __restrict__ Aq, const float* __restrict__ Bq,
                       const float* __restrict__ Wk,
                       const float* __restrict__ Wv, const float* __restrict__ Av, const float* __restrict__ Bv,
                       short* __restrict__ Wqe, short* __restrict__ Wke, short* __restrict__ Wve) {
    const int mode = blockIdx.y;
    const float* W = (mode == 0) ? Wq : (mode == 1) ? Wk : Wv;
    const float* A = (mode == 0) ? Aq : Av;
    const float* Bm = (mode == 0) ? Bq : Bv;
    short* outp = (mode == 0) ? Wqe : (mode == 1) ? Wke : Wve;
    int idx = blockIdx.x * 256 + threadIdx.x;        // 1M elems
    int n = idx >> 10, k = idx & 1023;
    float v = W[idx];
    if (mode != 1) {
        float s = 0.f;
#pragma unroll
        for (int r = 0; r < 8; ++r) s += Bm[n * 8 + r] * A[r * 1024 + k];
        v += 2.0f * s;
    }
    outp[idx] = f2bf(v);
}

// ---- projection GEMM (m97-style): global_load_lds staging, swizzled LDS ----
// z = 0: Q (scale 0.125, [b][h][t][d]); z=1: K (same); z=2: V -> [b][h][d][t]
// XCD tile-rectangle swizzle: HW XCD = bx (grid 8x32x3, 8|256). Each XCD owns a
// 4x8 (x,y) rectangle -> X panel read by 2 XCDs, W panel by 4: FETCH 68.7->~40MB,
// per-XCD working set (2MB X + 3MB W) ~= L2-resident -> cheaper barrier drains.
__global__ __launch_bounds__(256) void proj_gemm(
        const short* __restrict__ Xbf,
        const short* __restrict__ Wq, const short* __restrict__ Wk, const short* __restrict__ Wv,
        const float* __restrict__ bq, const float* __restrict__ bk, const float* __restrict__ bv,
        short* __restrict__ Qb, short* __restrict__ Kb, short* __restrict__ Vtb) {
    __shared__ __align__(16) char As[128 * 128];     // 128 rows x 64 bf16 (128B), swizzled
    __shared__ __align__(16) char Bs[128 * 128];

    const int mode = blockIdx.z;
    const short* Wbf = (mode == 0) ? Wq : (mode == 1) ? Wk : Wv;
    const float* bias = (mode == 0) ? bq : (mode == 1) ? bk : bv;
    short* outp = (mode == 0) ? Qb : (mode == 1) ? Kb : Vtb;
    const float scale = (mode == 0) ? 0.125f : 1.0f;  // HD^-0.5 folded into Q

    const int tid = threadIdx.x;
    const int wave = tid >> 6, lane = tid & 63;
    const int l15 = lane & 15, l4 = lane >> 4;
    // XCD rectangle swizzle (bijective): bx -> (gx, gq); by -> offsets
    const int bx = blockIdx.x, by = blockIdx.y;
    const int wx = (bx >> 2) * 4 + (by & 3);
    const int wy = (bx & 3) * 8 + (by >> 2);
    const int m0 = wy * 128, n0 = wx * 128;
    const int wm = (wave >> 1) * 64, wn = (wave & 1) * 64;

    const int lrow = lane >> 3;                      // 0..7
    const int lchunk = lane & 7;                     // 16B chunk
    const int srcoff = (lchunk ^ lrow) * 8;          // shorts
    char* ldsA = As + wave * 4096;
    char* ldsB = Bs + wave * 4096;

    const char* P1 = (mode == 2) ? As : Bs;
    const char* P2 = (mode == 2) ? Bs : As;
    const int o1 = (mode == 2) ? wm : wn;
    const int o2 = (mode == 2) ? wn : wm;

    f32x4 acc[4][4] = {};

    for (int k0 = 0; k0 < 1024; k0 += 64) {
        __syncthreads();
#pragma unroll
        for (int i = 0; i < 4; ++i) {
            int row = wave * 32 + i * 8 + lrow;
            gl_lds16(Xbf + (m0 + row) * 1024 + k0 + srcoff, ldsA + i * 1024);
            gl_lds16(Wbf + (n0 + row) * 1024 + k0 + srcoff, ldsB + i * 1024);
        }
        __syncthreads();
#pragma unroll
        for (int kk = 0; kk < 2; ++kk) {
            const int colb = kk * 64 + l4 * 16;
            bf16x8 f1[4], f2[4];
#pragma unroll
            for (int x = 0; x < 4; ++x) {
                int r1 = o1 + x * 16 + l15;
                f1[x] = *reinterpret_cast<const bf16x8*>(P1 + ((r1 * 128 + colb) ^ ((r1 & 7) << 4)));
                int r2 = o2 + x * 16 + l15;
                f2[x] = *reinterpret_cast<const bf16x8*>(P2 + ((r2 * 128 + colb) ^ ((r2 & 7) << 4)));
            }
#pragma unroll
            for (int x = 0; x < 4; ++x)
#pragma unroll
                for (int y = 0; y < 4; ++y)
                    acc[x][y] = __builtin_amdgcn_mfma_f32_16x16x32_bf16(f1[x], f2[y], acc[x][y], 0, 0, 0);
        }
    }

    if (mode != 2) {
#pragma unroll
        for (int x = 0; x < 4; ++x) {
            int gnb = n0 + wn + x * 16 + l4 * 4;
            int hh = gnb >> 6, d = gnb & 63;
            float4 bv4 = *reinterpret_cast<const float4*>(bias + gnb);
#pragma unroll
            for (int y = 0; y < 4; ++y) {
                int gm = m0 + wm + y * 16 + l15;
                int bb = gm >> 11, t = gm & 2047;
                short4v o;
                o[0] = f2bf((acc[x][y][0] + bv4.x) * scale);
                o[1] = f2bf((acc[x][y][1] + bv4.y) * scale);
                o[2] = f2bf((acc[x][y][2] + bv4.z) * scale);
                o[3] = f2bf((acc[x][y][3] + bv4.w) * scale);
                *reinterpret_cast<short4v*>(outp + ((bb * 16 + hh) * 2048 + t) * 64 + d) = o;
            }
        }
    } else {
#pragma unroll
        for (int x = 0; x < 4; ++x) {
            int gmb = m0 + wm + x * 16 + l4 * 4;
            int bb = gmb >> 11, t = gmb & 2047;
#pragma unroll
            for (int y = 0; y < 4; ++y) {
                int gn = n0 + wn + y * 16 + l15;
                int hh = gn >> 6, d = gn & 63;
                int tx = ((gn >> 3) & 1) << 2;       // half-swap for attn V read
                float bvs = bias[gn];
                short4v o;
                o[0] = f2bf(acc[x][y][0] + bvs);
                o[1] = f2bf(acc[x][y][1] + bvs);
                o[2] = f2bf(acc[x][y][2] + bvs);
                o[3] = f2bf(acc[x][y][3] + bvs);
                *reinterpret_cast<short4v*>(outp + ((bb * 16 + hh) * 64 + d) * 2048 + (t ^ tx)) = o;
            }
        }
    }
}

// ---- flash attention v10: counted-vmcnt pipeline, 4-buffer rotation ----
// (unchanged from round 16 — attn no longer the dominant dispatch)

#define STAGE(BUF, T) do {                                                           \
    const int _kv = (T) << 5;                                                        \
    gl_lds16(Kp + (_kv + krow) * 64 + kswz, MEM + (BUF) * 4096 + wv * 1024);         \
    gl_lds16(Vp + lane * 2048 + _kv + wv * 8, MEM + 16384 + (BUF) * 4096 + wv * 1024);\
} while (0)

#define SLICEJOB(QF0, QF1, OO, M, L, QBASE) do {                                     \
    f32x4 ss = {};                                                                   \
    ss = __builtin_amdgcn_mfma_f32_16x16x32_bf16(kf0, QF0, ss, 0, 0, 0);             \
    ss = __builtin_amdgcn_mfma_f32_16x16x32_bf16(kf1, QF1, ss, 0, 0, 0);             \
    float pr[4];                                                                     \
    if (kvs + 15 > (QBASE)) {                                                        \
        _Pragma("unroll")                                                            \
        for (int r = 0; r < 4; ++r) {                                                \
            float v = ss[r] + mv[r];                                                 \
            if (kvs + l4*4 + r > (QBASE) + l15) v = -1e30f;                          \
            pr[r] = v;                                                               \
        }                                                                            \
    } else {                                                                         \
        _Pragma("unroll")                                                            \
        for (int r = 0; r < 4; ++r) pr[r] = ss[r] + mv[r];                           \
    }                                                                                \
    float tl = fmaxf(fmaxf(pr[0], pr[1]), fmaxf(pr[2], pr[3]));                      \
    if (!__all(tl - (M) <= 8.0f)) {                                                  \
        float tm = tl;                                                               \
        tm = fmaxf(tm, __shfl_xor(tm, 16));                                          \
        tm = fmaxf(tm, __shfl_xor(tm, 32));                                          \
        float mn = fmaxf((M), tm);                                                   \
        float al = __expf((M) - mn);                                                 \
        M = mn; L *= al;                                                             \
        _Pragma("unroll")                                                            \
        for (int dt = 0; dt < 4; ++dt)                                               \
            _Pragma("unroll")                                                        \
            for (int r = 0; r < 4; ++r) OO[dt][r] *= al;                             \
    }                                                                                \
    _Pragma("unroll")                                                                \
    for (int r = 0; r < 4; ++r) pr[r] = __expf(pr[r] - (M));                         \
    L += (pr[0] + pr[1]) + (pr[2] + pr[3]);                                          \
    short4v pa;                                                                      \
    _Pragma("unroll")                                                                \
    for (int r = 0; r < 4; ++r) pa[r] = f2bf(pr[r]);                                 \
    _Pragma("unroll")                                                                \
    for (int dt = 0; dt < 4; ++dt)                                                   \
        OO[dt] = __builtin_amdgcn_mfma_f32_16x16x16bf16_1k(vf[dt], pa, OO[dt], 0, 0, 0); \
} while (0)

// LDS (bytes): K 4-buf [4][4096] @0 | V 4-buf [4][4096] @16384 | mask 8192 @32768 = 40960
// merge regions reuse @0 after the stream loop (20480 B, over dead K/V buffers)
__global__ __launch_bounds__(256, 4) void attn(
        const short* __restrict__ Qb, const short* __restrict__ Kb,
        const short* __restrict__ Vt, const float* __restrict__ amask,
        float* __restrict__ outp) {
    __shared__ __align__(16) char MEM[40960];

    const int tid = threadIdx.x, wv = tid >> 6, lane = tid & 63;
    const int l15 = lane & 15, l4 = lane >> 4;
    // XCD-chunked + bit-mixed j: robust CU-level balance under round-robin fill
    const int xcd = blockIdx.x & 7;
    const int k   = blockIdx.x >> 3;                 // 0..127 within XCD
    const int j   = ((k >> 5) << 3) | ((k & 3) << 1) | ((k >> 4) & 1);  // 0..31
    const int bh  = xcd * 4 + ((k >> 2) & 3);        // 4 bh per XCD (L2 locality)
    const int p  = wv & 1;                           // pair in block
    const int s  = wv >> 1;                          // key-slice
    const int i  = 2 * j + p;                        // pair index 0..63
    const int b = bh >> 4, h = bh & 15;

    const short* Qp = Qb + bh * TT * HDD;
    const short* Kp = Kb + bh * TT * HDD;
    const short* Vp = Vt + bh * HDD * TT;
    const float* mp = amask + b * TT;
    float* mlds = (float*)(MEM + 32768);

    const int qbaseA = (127 - i) << 4;
    const int qbaseB = i << 4;
    const int nkA = ((qbaseA + 15 - 16 * s) >> 5) + 1;   // slice-aware causal bounds
    const int nkB = ((qbaseB + 15 - 16 * s) >> 5) + 1;   // (0 when slice fully masked)
    const int NT = ((127 - 2 * j) * 16 + 47) >> 5;       // block stream extent (>= 33)

    // staging lane geometry: K rows [wv*8,+8) pre-swizzled; V chunk wv, d=lane
    const int krow = wv * 8 + (lane >> 3);
    const int kswz = ((lane & 7) ^ (lane >> 3)) * 8;     // shorts

    // LDS read offsets (bytes)
    const int kb0 = (16 * s + l15) * 128 + ((l4 ^ (l15 & 7)) << 4);
    const int vb0 = (2 * s + (l4 >> 1)) * 1024 + l15 * 16 + (((l4 & 1) ^ (l15 >> 3)) << 3);

    // prologue: mask -> LDS (whole row for this b)
    {
        int mi8 = tid * 8;
        float4 a = *reinterpret_cast<const float4*>(mp + mi8);
        float4 c = *reinterpret_cast<const float4*>(mp + mi8 + 4);
        *reinterpret_cast<float4*>(mlds + mi8) = a;
        *reinterpret_cast<float4*>(mlds + mi8 + 4) = c;
    }

    bf16x8 qfA0 = *reinterpret_cast<const bf16x8*>(Qp + (qbaseA + l15) * 64 + l4 * 8);
    bf16x8 qfA1 = *reinterpret_cast<const bf16x8*>(Qp + (qbaseA + l15) * 64 + 32 + l4 * 8);
    bf16x8 qfB0 = *reinterpret_cast<const bf16x8*>(Qp + (qbaseB + l15) * 64 + l4 * 8);
    bf16x8 qfB1 = *reinterpret_cast<const bf16x8*>(Qp + (qbaseB + l15) * 64 + 32 + l4 * 8);

    f32x4 OA[4] = {}, OB[4] = {};
    float MA = -1e30f, LA = 0.f, MB = -1e30f, LB = 0.f;

    STAGE(0, 0);                                     // tiles 0,1 in flight
    STAGE(1, 1);                                     // (NT >= 33, both exist)
    asm volatile("s_waitcnt lgkmcnt(0)" ::: "memory");   // mask writes retired

    int cur = 0;                                     // t % 4
    for (int t = 0; t < NT; ++t) {
        if (t + 2 < NT) {
            int nb = cur + 2; if (nb >= 4) nb -= 4;
            STAGE(nb, t + 2);                        // in flight: t, t+1, t+2
            asm volatile("s_waitcnt vmcnt(4)" ::: "memory");   // tile t landed
        } else if (t + 1 < NT) {
            asm volatile("s_waitcnt vmcnt(2)" ::: "memory");
        } else {
            asm volatile("s_waitcnt vmcnt(0)" ::: "memory");
        }
        asm volatile("s_barrier" ::: "memory");      // tile-t visible to all waves
        if (t < nkA) {
            const char* Kcur = MEM + cur * 4096;
            const char* Vcur = MEM + 16384 + cur * 4096;
            bf16x8 kf0 = *reinterpret_cast<const bf16x8*>(Kcur + kb0);
            bf16x8 kf1 = *reinterpret_cast<const bf16x8*>(Kcur + (kb0 ^ 64));
            short4v vf[4];
#pragma unroll
            for (int dt = 0; dt < 4; ++dt)
                vf[dt] = *reinterpret_cast<const short4v*>(Vcur + vb0 + dt * 256);
            const int kvs = (t << 5) + 16 * s;
            float4 mv = *reinterpret_cast<const float4*>(mlds + kvs + l4 * 4);
            SLICEJOB(qfA0, qfA1, OA, MA, LA, qbaseA);
            if (t < nkB) SLICEJOB(qfB0, qfB1, OB, MB, LB, qbaseB);
        }
        ++cur; if (cur == 4) cur = 0;
    }
    asm volatile("s_barrier" ::: "memory");          // loop reads done before merge reuse

    // reduce l across l4 groups (per slice)
    LA += __shfl_xor(LA, 16); LA += __shfl_xor(LA, 32);
    LB += __shfl_xor(LB, 16); LB += __shfl_xor(LB, 32);

    // disjoint-key merge: slice-1 posts, slice-0 merges + writes
    float* mg = (float*)MEM + p * 2560 + lane * 40;  // 160B/lane, 16B-aligned chunks
    if (s) {
#pragma unroll
        for (int dt = 0; dt < 4; ++dt) *reinterpret_cast<f32x4*>(mg + dt * 4) = OA[dt];
        mg[16] = MA; mg[17] = LA;
#pragma unroll
        for (int dt = 0; dt < 4; ++dt) *reinterpret_cast<f32x4*>(mg + 20 + dt * 4) = OB[dt];
        mg[36] = MB; mg[37] = LB;
    }
    __syncthreads();
    if (!s) {
        {
            float m1 = mg[16], l1 = mg[17];
            float ms = fmaxf(MA, m1);
            float e0 = __expf(MA - ms), e1 = __expf(m1 - ms);
            float inv = 1.0f / (LA * e0 + l1 * e1);
            int tA = qbaseA + l15;
#pragma unroll
            for (int dt = 0; dt < 4; ++dt) {
                f32x4 o1 = *reinterpret_cast<const f32x4*>(mg + dt * 4);
                float4 o;
                o.x = (OA[dt][0] * e0 + o1[0] * e1) * inv;
                o.y = (OA[dt][1] * e0 + o1[1] * e1) * inv;
                o.z = (OA[dt][2] * e0 + o1[2] * e1) * inv;
                o.w = (OA[dt][3] * e0 + o1[3] * e1) * inv;
                *reinterpret_cast<float4*>(outp + (b * 2048 + tA) * 1024 + h * 64 + dt * 16 + l4 * 4) = o;
            }
        }
        {
            float m1 = mg[36], l1 = mg[37];
            float ms = fmaxf(MB, m1);
            float e0 = __expf(MB - ms), e1 = __expf(m1 - ms);
            float inv = 1.0f / (LB * e0 + l1 * e1);
            int tB = qbaseB + l15;
#pragma unroll
            for (int dt = 0; dt < 4; ++dt) {
                f32x4 o1 = *reinterpret_cast<const f32x4*>(mg + 20 + dt * 4);
                float4 o;
                o.x = (OB[dt][0] * e0 + o1[0] * e1) * inv;
                o.y = (OB[dt][1] * e0 + o1[1] * e1) * inv;
                o.z = (OB[dt][2] * e0 + o1[2] * e1) * inv;
                o.w = (OB[dt][3] * e0 + o1[3] * e1) * inv;
                *reinterpret_cast<float4*>(outp + (b * 2048 + tB) * 1024 + h * 64 + dt * 16 + l4 * 4) = o;
            }
        }
    }
}

extern "C" void kernel_launch(void* const* d_in, const int* in_sizes, int n_in,
                              void* d_out, int out_size, void* d_ws, size_t ws_size,
                              hipStream_t stream) {
    const float* hidden = (const float*)d_in[0];
    const float* amask  = (const float*)d_in[1];
    const float* Wq = (const float*)d_in[2];
    const float* bq = (const float*)d_in[3];
    const float* Aq = (const float*)d_in[4];
    const float* Bq = (const float*)d_in[5];
    const float* Wk = (const float*)d_in[6];
    const float* bk = (const float*)d_in[7];
    const float* Wv = (const float*)d_in[8];
    const float* bv = (const float*)d_in[9];
    const float* Av = (const float*)d_in[10];
    const float* Bv = (const float*)d_in[11];
    float* outp = (float*)d_out;

    char* ws = (char*)d_ws;
    short* Xbf = (short*)(ws);                 // 8 MB  [4096][1024] bf16
    short* Wqe = (short*)(ws + (8 << 20));     // 2 MB
    short* Wke = (short*)(ws + (10 << 20));    // 2 MB
    short* Wve = (short*)(ws + (12 << 20));    // 2 MB
    short* Qb  = (short*)(ws + (14 << 20));    // 8 MB  [b][h][t][d]
    short* Kb  = (short*)(ws + (22 << 20));    // 8 MB  [b][h][t][d]
    short* Vtb = (short*)(ws + (30 << 20));    // 8 MB  [b][h][d][t] (half-swapped)

    cvt_hidden<<<4096, 256, 0, stream>>>(hidden, Xbf);
    prep_w<<<dim3(4096, 3), 256, 0, stream>>>(Wq, Aq, Bq, Wk, Wv, Av, Bv, Wqe, Wke, Wve);
    proj_gemm<<<dim3(8, 32, 3), 256, 0, stream>>>(Xbf, Wqe, Wke, Wve, bq, bk, bv, Qb, Kb, Vtb);
    attn<<<1024, 256, 0, stream>>>(Qb, Kb, Vtb, amask, outp);
}

// Round 19
// 104.367 us; speedup vs baseline: 2.0700x; 1.0403x over previous
//
#include <hip/hip_runtime.h>
#include <hip/hip_bf16.h>

#define BB 2
#define TT 2048
#define DMM 1024
#define HH 16
#define HDD 64

typedef __attribute__((ext_vector_type(8))) short bf16x8;
typedef __attribute__((ext_vector_type(4))) short short4v;
typedef __attribute__((ext_vector_type(4))) float f32x4;

static __device__ __forceinline__ short f2bf(float f) {
    __hip_bfloat16 h = __float2bfloat16(f);
    return *reinterpret_cast<short*>(&h);
}

static __device__ __forceinline__ float ex2(float x) {
    return __builtin_amdgcn_exp2f(x);    // v_exp_f32: D = 2^S0
}

static __device__ __forceinline__ void gl_lds16(const void* g, void* l) {
    __builtin_amdgcn_global_load_lds(
        (const __attribute__((address_space(1))) void*)g,
        (__attribute__((address_space(3))) void*)l, 16, 0, 0);
}

// ---- hidden f32 -> bf16 (4 elems/thread) ----
__global__ void cvt_hidden(const float* __restrict__ x, short* __restrict__ y) {
    int i = blockIdx.x * 256 + threadIdx.x;          // 1M threads, 4M elems
    float4 v = reinterpret_cast<const float4*>(x)[i];
    short4v o;
    o[0] = f2bf(v.x); o[1] = f2bf(v.y); o[2] = f2bf(v.z); o[3] = f2bf(v.w);
    reinterpret_cast<short4v*>(y)[i] = o;
}

// ---- W_eff = W + 2.0 * B@A (Q,V) or plain W (K), cast bf16; grid.y = mode ----
__global__ void prep_w(const float* __restrict__ Wq, const float* __restrict__ Aq, const float* __restrict__ Bq,
                       const float* __restrict__ Wk,
                       const float* __restrict__ Wv, const float* __restrict__ Av, const float* __restrict__ Bv,
                       short* __restrict__ Wqe, short* __restrict__ Wke, short* __restrict__ Wve) {
    const int mode = blockIdx.y;
    const float* W = (mode == 0) ? Wq : (mode == 1) ? Wk : Wv;
    const float* A = (mode == 0) ? Aq : Av;
    const float* Bm = (mode == 0) ? Bq : Bv;
    short* outp = (mode == 0) ? Wqe : (mode == 1) ? Wke : Wve;
    int idx = blockIdx.x * 256 + threadIdx.x;        // 1M elems
    int n = idx >> 10, k = idx & 1023;
    float v = W[idx];
    if (mode != 1) {
        float s = 0.f;
#pragma unroll
        for (int r = 0; r < 8; ++r) s += Bm[n * 8 + r] * A[r * 1024 + k];
        v += 2.0f * s;
    }
    outp[idx] = f2bf(v);
}

// ---- projection GEMM v2: 64M x 128N tile, 6 blocks/CU (occupancy play) ----
// grid (8, 64, 3); z = 0: Q (scale 0.125*log2e, [b][h][t][d]); z=1: K; z=2: V^T.
// Mode-specialized loops keep packed 8B epilogue stores (operand-order swap).
// XCD 2x32 rectangle: X panel read by 2 XCDs, W panel by 2 -> FETCH ~28MB.
__global__ __launch_bounds__(256, 5) void proj_gemm(
        const short* __restrict__ Xbf,
        const short* __restrict__ Wq, const short* __restrict__ Wk, const short* __restrict__ Wv,
        const float* __restrict__ bq, const float* __restrict__ bk, const float* __restrict__ bv,
        short* __restrict__ Qb, short* __restrict__ Kb, short* __restrict__ Vtb) {
    __shared__ __align__(16) char As[64 * 128];      // X tile: 64 rows x 64 bf16, swizzled
    __shared__ __align__(16) char Bs[128 * 128];     // W tile: 128 rows x 64 bf16, swizzled

    const int mode = blockIdx.z;
    const short* Wbf = (mode == 0) ? Wq : (mode == 1) ? Wk : Wv;
    const float* bias = (mode == 0) ? bq : (mode == 1) ? bk : bv;
    short* outp = (mode == 0) ? Qb : (mode == 1) ? Kb : Vtb;
    const float scale = (mode == 0) ? 0.18033688f : 1.0f;  // HD^-0.5 * log2(e) folded into Q

    const int tid = threadIdx.x;
    const int wave = tid >> 6, lane = tid & 63;
    const int l15 = lane & 15, l4 = lane >> 4;
    // XCD rectangle swizzle (bijective): XCD = bx owns 2 W-panels x 32 X-panels
    const int bx = blockIdx.x, by = blockIdx.y;
    const int wx = 2 * (bx & 3) + (by & 1);          // W panel 0..7
    const int wy = (bx >> 2) * 32 + (by >> 1);       // X panel 0..63
    const int m0 = wy * 64, n0 = wx * 128;
    const int wm = (wave >> 1) * 32, wn = (wave & 1) * 64;

    const int lrow8 = lane >> 3;                     // 0..7
    const int lchunk = lane & 7;                     // 16B chunk
    const int srcoff = (lchunk ^ lrow8) * 8;         // shorts (pre-swizzled source)
    char* ldsA = As + wave * 2048;
    char* ldsB = Bs + wave * 4096;

#define PROJ_STAGE(K0) do {                                                          \
    _Pragma("unroll")                                                                \
    for (int i = 0; i < 2; ++i)                                                      \
        gl_lds16(Xbf + (m0 + wave * 16 + i * 8 + lrow8) * 1024 + (K0) + srcoff,      \
                 ldsA + i * 1024);                                                   \
    _Pragma("unroll")                                                                \
    for (int i = 0; i < 4; ++i)                                                      \
        gl_lds16(Wbf + (n0 + wave * 32 + i * 8 + lrow8) * 1024 + (K0) + srcoff,      \
                 ldsB + i * 1024);                                                   \
} while (0)

#define PROJ_FRAGS(KK)                                                               \
    const int colb = (KK) * 64 + l4 * 16;                                            \
    bf16x8 wf[4], xf[2];                                                             \
    _Pragma("unroll")                                                                \
    for (int w = 0; w < 4; ++w) {                                                    \
        int r = wn + w * 16 + l15;                                                   \
        wf[w] = *reinterpret_cast<const bf16x8*>(Bs + ((r * 128 + colb) ^ ((r & 7) << 4))); \
    }                                                                                \
    _Pragma("unroll")                                                                \
    for (int x = 0; x < 2; ++x) {                                                    \
        int r = wm + x * 16 + l15;                                                   \
        xf[x] = *reinterpret_cast<const bf16x8*>(As + ((r * 128 + colb) ^ ((r & 7) << 4))); \
    }

    if (mode != 2) {
        // C^T orientation: C rows = features (wf first operand), cols = tokens
        f32x4 acc[4][2] = {};
        for (int k0 = 0; k0 < 1024; k0 += 64) {
            __syncthreads();
            PROJ_STAGE(k0);
            __syncthreads();
#pragma unroll
            for (int kk = 0; kk < 2; ++kk) {
                PROJ_FRAGS(kk);
#pragma unroll
                for (int w = 0; w < 4; ++w)
#pragma unroll
                    for (int x = 0; x < 2; ++x)
                        acc[w][x] = __builtin_amdgcn_mfma_f32_16x16x32_bf16(wf[w], xf[x], acc[w][x], 0, 0, 0);
            }
        }
#pragma unroll
        for (int w = 0; w < 4; ++w) {
            int gnb = n0 + wn + w * 16 + l4 * 4;     // 4 consecutive features
            int hh = gnb >> 6, d = gnb & 63;
            float4 bv4 = *reinterpret_cast<const float4*>(bias + gnb);
#pragma unroll
            for (int x = 0; x < 2; ++x) {
                int gm = m0 + wm + x * 16 + l15;
                int bb = gm >> 11, t = gm & 2047;
                short4v o;
                o[0] = f2bf((acc[w][x][0] + bv4.x) * scale);
                o[1] = f2bf((acc[w][x][1] + bv4.y) * scale);
                o[2] = f2bf((acc[w][x][2] + bv4.z) * scale);
                o[3] = f2bf((acc[w][x][3] + bv4.w) * scale);
                *reinterpret_cast<short4v*>(outp + ((bb * 16 + hh) * 2048 + t) * 64 + d) = o;
            }
        }
    } else {
        // C orientation: rows = tokens, cols = features; V^T [d][t] with half-swap
        f32x4 acc[2][4] = {};
        for (int k0 = 0; k0 < 1024; k0 += 64) {
            __syncthreads();
            PROJ_STAGE(k0);
            __syncthreads();
#pragma unroll
            for (int kk = 0; kk < 2; ++kk) {
                PROJ_FRAGS(kk);
#pragma unroll
                for (int x = 0; x < 2; ++x)
#pragma unroll
                    for (int w = 0; w < 4; ++w)
                        acc[x][w] = __builtin_amdgcn_mfma_f32_16x16x32_bf16(xf[x], wf[w], acc[x][w], 0, 0, 0);
            }
        }
#pragma unroll
        for (int x = 0; x < 2; ++x) {
            int gmb = m0 + wm + x * 16 + l4 * 4;     // 4 consecutive tokens
            int bb = gmb >> 11, t = gmb & 2047;
#pragma unroll
            for (int w = 0; w < 4; ++w) {
                int gn = n0 + wn + w * 16 + l15;
                int hh = gn >> 6, d = gn & 63;
                int tx = ((gn >> 3) & 1) << 2;       // half-swap for attn V read
                float bvs = bias[gn];
                short4v o;
                o[0] = f2bf(acc[x][w][0] + bvs);
                o[1] = f2bf(acc[x][w][1] + bvs);
                o[2] = f2bf(acc[x][w][2] + bvs);
                o[3] = f2bf(acc[x][w][3] + bvs);
                *reinterpret_cast<short4v*>(outp + ((bb * 16 + hh) * 64 + d) * 2048 + (t ^ tx)) = o;
            }
        }
    }
}

// ---- flash attention v11: v10 pipeline + exp2-domain softmax ----
// Q pre-scaled by 0.125*log2e (proj); mask staged *log2e; ex2() throughout;
// defer threshold 8 ln-units = 11.5415603 log2-units. Else identical to v10.

#define STAGE(BUF, T) do {                                                           \
    const int _kv = (T) << 5;                                                        \
    gl_lds16(Kp + (_kv + krow) * 64 + kswz, MEM + (BUF) * 4096 + wv * 1024);         \
    gl_lds16(Vp + lane * 2048 + _kv + wv * 8, MEM + 16384 + (BUF) * 4096 + wv * 1024);\
} while (0)

#define SLICEJOB(QF0, QF1, OO, M, L, QBASE) do {                                     \
    f32x4 ss = {};                                                                   \
    ss = __builtin_amdgcn_mfma_f32_16x16x32_bf16(kf0, QF0, ss, 0, 0, 0);             \
    ss = __builtin_amdgcn_mfma_f32_16x16x32_bf16(kf1, QF1, ss, 0, 0, 0);             \
    float pr[4];                                                                     \
    if (kvs + 15 > (QBASE)) {                                                        \
        _Pragma("unroll")                                                            \
        for (int r = 0; r < 4; ++r) {                                                \
            float v = ss[r] + mv[r];                                                 \
            if (kvs + l4*4 + r > (QBASE) + l15) v = -1e30f;                          \
            pr[r] = v;                                                               \
        }                                                                            \
    } else {                                                                         \
        _Pragma("unroll")                                                            \
        for (int r = 0; r < 4; ++r) pr[r] = ss[r] + mv[r];                           \
    }                                                                                \
    float tl = fmaxf(fmaxf(pr[0], pr[1]), fmaxf(pr[2], pr[3]));                      \
    if (!__all(tl - (M) <= 11.5415603f)) {                                           \
        float tm = tl;                                                               \
        tm = fmaxf(tm, __shfl_xor(tm, 16));                                          \
        tm = fmaxf(tm, __shfl_xor(tm, 32));                                          \
        float mn = fmaxf((M), tm);                                                   \
        float al = ex2((M) - mn);                                                    \
        M = mn; L *= al;                                                             \
        _Pragma("unroll")                                                            \
        for (int dt = 0; dt < 4; ++dt)                                               \
            _Pragma("unroll")                                                        \
            for (int r = 0; r < 4; ++r) OO[dt][r] *= al;                             \
    }                                                                                \
    _Pragma("unroll")                                                                \
    for (int r = 0; r < 4; ++r) pr[r] = ex2(pr[r] - (M));                            \
    L += (pr[0] + pr[1]) + (pr[2] + pr[3]);                                          \
    short4v pa;                                                                      \
    _Pragma("unroll")                                                                \
    for (int r = 0; r < 4; ++r) pa[r] = f2bf(pr[r]);                                 \
    _Pragma("unroll")                                                                \
    for (int dt = 0; dt < 4; ++dt)                                                   \
        OO[dt] = __builtin_amdgcn_mfma_f32_16x16x16bf16_1k(vf[dt], pa, OO[dt], 0, 0, 0); \
} while (0)

// LDS (bytes): K 4-buf [4][4096] @0 | V 4-buf [4][4096] @16384 | mask 8192 @32768 = 40960
// merge regions reuse @0 after the stream loop (20480 B, over dead K/V buffers)
__global__ __launch_bounds__(256, 4) void attn(
        const short* __restrict__ Qb, const short* __restrict__ Kb,
        const short* __restrict__ Vt, const float* __restrict__ amask,
        float* __restrict__ outp) {
    __shared__ __align__(16) char MEM[40960];

    const int tid = threadIdx.x, wv = tid >> 6, lane = tid & 63;
    const int l15 = lane & 15, l4 = lane >> 4;
    // XCD-chunked + bit-mixed j: robust CU-level balance under round-robin fill
    const int xcd = blockIdx.x & 7;
    const int k   = blockIdx.x >> 3;                 // 0..127 within XCD
    const int j   = ((k >> 5) << 3) | ((k & 3) << 1) | ((k >> 4) & 1);  // 0..31
    const int bh  = xcd * 4 + ((k >> 2) & 3);        // 4 bh per XCD (L2 locality)
    const int p  = wv & 1;                           // pair in block
    const int s  = wv >> 1;                          // key-slice
    const int i  = 2 * j + p;                        // pair index 0..63
    const int b = bh >> 4, h = bh & 15;

    const short* Qp = Qb + bh * TT * HDD;
    const short* Kp = Kb + bh * TT * HDD;
    const short* Vp = Vt + bh * HDD * TT;
    const float* mp = amask + b * TT;
    float* mlds = (float*)(MEM + 32768);

    const int qbaseA = (127 - i) << 4;
    const int qbaseB = i << 4;
    const int nkA = ((qbaseA + 15 - 16 * s) >> 5) + 1;   // slice-aware causal bounds
    const int nkB = ((qbaseB + 15 - 16 * s) >> 5) + 1;   // (0 when slice fully masked)
    const int NT = ((127 - 2 * j) * 16 + 47) >> 5;       // block stream extent (>= 33)

    // staging lane geometry: K rows [wv*8,+8) pre-swizzled; V chunk wv, d=lane
    const int krow = wv * 8 + (lane >> 3);
    const int kswz = ((lane & 7) ^ (lane >> 3)) * 8;     // shorts

    // LDS read offsets (bytes)
    const int kb0 = (16 * s + l15) * 128 + ((l4 ^ (l15 & 7)) << 4);
    const int vb0 = (2 * s + (l4 >> 1)) * 1024 + l15 * 16 + (((l4 & 1) ^ (l15 >> 3)) << 3);

    // prologue: mask -> LDS (whole row for this b), scaled to log2 domain
    {
        int mi8 = tid * 8;
        float4 a = *reinterpret_cast<const float4*>(mp + mi8);
        float4 c = *reinterpret_cast<const float4*>(mp + mi8 + 4);
        a.x *= 1.44269504f; a.y *= 1.44269504f; a.z *= 1.44269504f; a.w *= 1.44269504f;
        c.x *= 1.44269504f; c.y *= 1.44269504f; c.z *= 1.44269504f; c.w *= 1.44269504f;
        *reinterpret_cast<float4*>(mlds + mi8) = a;
        *reinterpret_cast<float4*>(mlds + mi8 + 4) = c;
    }

    bf16x8 qfA0 = *reinterpret_cast<const bf16x8*>(Qp + (qbaseA + l15) * 64 + l4 * 8);
    bf16x8 qfA1 = *reinterpret_cast<const bf16x8*>(Qp + (qbaseA + l15) * 64 + 32 + l4 * 8);
    bf16x8 qfB0 = *reinterpret_cast<const bf16x8*>(Qp + (qbaseB + l15) * 64 + l4 * 8);
    bf16x8 qfB1 = *reinterpret_cast<const bf16x8*>(Qp + (qbaseB + l15) * 64 + 32 + l4 * 8);

    f32x4 OA[4] = {}, OB[4] = {};
    float MA = -1e30f, LA = 0.f, MB = -1e30f, LB = 0.f;

    STAGE(0, 0);                                     // tiles 0,1 in flight
    STAGE(1, 1);                                     // (NT >= 33, both exist)
    asm volatile("s_waitcnt lgkmcnt(0)" ::: "memory");   // mask writes retired

    int cur = 0;                                     // t % 4
    for (int t = 0; t < NT; ++t) {
        if (t + 2 < NT) {
            int nb = cur + 2; if (nb >= 4) nb -= 4;
            STAGE(nb, t + 2);                        // in flight: t, t+1, t+2
            asm volatile("s_waitcnt vmcnt(4)" ::: "memory");   // tile t landed
        } else if (t + 1 < NT) {
            asm volatile("s_waitcnt vmcnt(2)" ::: "memory");
        } else {
            asm volatile("s_waitcnt vmcnt(0)" ::: "memory");
        }
        asm volatile("s_barrier" ::: "memory");      // tile-t visible to all waves
        if (t < nkA) {
            const char* Kcur = MEM + cur * 4096;
            const char* Vcur = MEM + 16384 + cur * 4096;
            bf16x8 kf0 = *reinterpret_cast<const bf16x8*>(Kcur + kb0);
            bf16x8 kf1 = *reinterpret_cast<const bf16x8*>(Kcur + (kb0 ^ 64));
            short4v vf[4];
#pragma unroll
            for (int dt = 0; dt < 4; ++dt)
                vf[dt] = *reinterpret_cast<const short4v*>(Vcur + vb0 + dt * 256);
            const int kvs = (t << 5) + 16 * s;
            float4 mv = *reinterpret_cast<const float4*>(mlds + kvs + l4 * 4);
            SLICEJOB(qfA0, qfA1, OA, MA, LA, qbaseA);
            if (t < nkB) SLICEJOB(qfB0, qfB1, OB, MB, LB, qbaseB);
        }
        ++cur; if (cur == 4) cur = 0;
    }
    asm volatile("s_barrier" ::: "memory");          // loop reads done before merge reuse

    // reduce l across l4 groups (per slice)
    LA += __shfl_xor(LA, 16); LA += __shfl_xor(LA, 32);
    LB += __shfl_xor(LB, 16); LB += __shfl_xor(LB, 32);

    // disjoint-key merge: slice-1 posts, slice-0 merges + writes
    float* mg = (float*)MEM + p * 2560 + lane * 40;  // 160B/lane, 16B-aligned chunks
    if (s) {
#pragma unroll
        for (int dt = 0; dt < 4; ++dt) *reinterpret_cast<f32x4*>(mg + dt * 4) = OA[dt];
        mg[16] = MA; mg[17] = LA;
#pragma unroll
        for (int dt = 0; dt < 4; ++dt) *reinterpret_cast<f32x4*>(mg + 20 + dt * 4) = OB[dt];
        mg[36] = MB; mg[37] = LB;
    }
    __syncthreads();
    if (!s) {
        {
            float m1 = mg[16], l1 = mg[17];
            float ms = fmaxf(MA, m1);
            float e0 = ex2(MA - ms), e1 = ex2(m1 - ms);
            float inv = 1.0f / (LA * e0 + l1 * e1);
            int tA = qbaseA + l15;
#pragma unroll
            for (int dt = 0; dt < 4; ++dt) {
                f32x4 o1 = *reinterpret_cast<const f32x4*>(mg + dt * 4);
                float4 o;
                o.x = (OA[dt][0] * e0 + o1[0] * e1) * inv;
                o.y = (OA[dt][1] * e0 + o1[1] * e1) * inv;
                o.z = (OA[dt][2] * e0 + o1[2] * e1) * inv;
                o.w = (OA[dt][3] * e0 + o1[3] * e1) * inv;
                *reinterpret_cast<float4*>(outp + (b * 2048 + tA) * 1024 + h * 64 + dt * 16 + l4 * 4) = o;
            }
        }
        {
            float m1 = mg[36], l1 = mg[37];
            float ms = fmaxf(MB, m1);
            float e0 = ex2(MB - ms), e1 = ex2(m1 - ms);
            float inv = 1.0f / (LB * e0 + l1 * e1);
            int tB = qbaseB + l15;
#pragma unroll
            for (int dt = 0; dt < 4; ++dt) {
                f32x4 o1 = *reinterpret_cast<const f32x4*>(mg + 20 + dt * 4);
                float4 o;
                o.x = (OB[dt][0] * e0 + o1[0] * e1) * inv;
                o.y = (OB[dt][1] * e0 + o1[1] * e1) * inv;
                o.z = (OB[dt][2] * e0 + o1[2] * e1) * inv;
                o.w = (OB[dt][3] * e0 + o1[3] * e1) * inv;
                *reinterpret_cast<float4*>(outp + (b * 2048 + tB) * 1024 + h * 64 + dt * 16 + l4 * 4) = o;
            }
        }
    }
}

extern "C" void kernel_launch(void* const* d_in, const int* in_sizes, int n_in,
                              void* d_out, int out_size, void* d_ws, size_t ws_size,
                              hipStream_t stream) {
    const float* hidden = (const float*)d_in[0];
    const float* amask  = (const float*)d_in[1];
    const float* Wq = (const float*)d_in[2];
    const float* bq = (const float*)d_in[3];
    const float* Aq = (const float*)d_in[4];
    const float* Bq = (const float*)d_in[5];
    const float* Wk = (const float*)d_in[6];
    const float* bk = (const float*)d_in[7];
    const float* Wv = (const float*)d_in[8];
    const float* bv = (const float*)d_in[9];
    const float* Av = (const float*)d_in[10];
    const float* Bv = (const float*)d_in[11];
    float* outp = (float*)d_out;

    char* ws = (char*)d_ws;
    short* Xbf = (short*)(ws);                 // 8 MB  [4096][1024] bf16
    short* Wqe = (short*)(ws + (8 << 20));     // 2 MB
    short* Wke = (short*)(ws + (10 << 20));    // 2 MB
    short* Wve = (short*)(ws + (12 << 20));    // 2 MB
    short* Qb  = (short*)(ws + (14 << 20));    // 8 MB  [b][h][t][d] (pre-scaled by 0.125*log2e)
    short* Kb  = (short*)(ws + (22 << 20));    // 8 MB  [b][h][t][d]
    short* Vtb = (short*)(ws + (30 << 20));    // 8 MB  [b][h][d][t] (half-swapped)

    cvt_hidden<<<4096, 256, 0, stream>>>(hidden, Xbf);
    prep_w<<<dim3(4096, 3), 256, 0, stream>>>(Wq, Aq, Bq, Wk, Wv, Av, Bv, Wqe, Wke, Wve);
    proj_gemm<<<dim3(8, 64, 3), 256, 0, stream>>>(Xbf, Wqe, Wke, Wve, bq, bk, bv, Qb, Kb, Vtb);
    attn<<<1024, 256, 0, stream>>>(Qb, Kb, Vtb, amask, outp);
}

// Round 20
// 104.236 us; speedup vs baseline: 2.0727x; 1.0013x over previous
//
#include <hip/hip_runtime.h>
#include <hip/hip_bf16.h>

#define BB 2
#define TT 2048
#define DMM 1024
#define HH 16
#define HDD 64

typedef __attribute__((ext_vector_type(8))) short bf16x8;
typedef __attribute__((ext_vector_type(4))) short short4v;
typedef __attribute__((ext_vector_type(4))) float f32x4;

static __device__ __forceinline__ short f2bf(float f) {
    __hip_bfloat16 h = __float2bfloat16(f);
    return *reinterpret_cast<short*>(&h);
}

static __device__ __forceinline__ float ex2(float x) {
    return __builtin_amdgcn_exp2f(x);    // v_exp_f32: D = 2^S0
}

static __device__ __forceinline__ void gl_lds16(const void* g, void* l) {
    __builtin_amdgcn_global_load_lds(
        (const __attribute__((address_space(1))) void*)g,
        (__attribute__((address_space(3))) void*)l, 16, 0, 0);
}

// ---- hidden f32 -> bf16 (4 elems/thread) ----
__global__ void cvt_hidden(const float* __restrict__ x, short* __restrict__ y) {
    int i = blockIdx.x * 256 + threadIdx.x;          // 1M threads, 4M elems
    float4 v = reinterpret_cast<const float4*>(x)[i];
    short4v o;
    o[0] = f2bf(v.x); o[1] = f2bf(v.y); o[2] = f2bf(v.z); o[3] = f2bf(v.w);
    reinterpret_cast<short4v*>(y)[i] = o;
}

// ---- W_eff = W + 2.0 * B@A (Q,V) or plain W (K), cast bf16; grid.y = mode ----
__global__ void prep_w(const float* __restrict__ Wq, const float* __restrict__ Aq, const float* __restrict__ Bq,
                       const float* __restrict__ Wk,
                       const float* __restrict__ Wv, const float* __restrict__ Av, const float* __restrict__ Bv,
                       short* __restrict__ Wqe, short* __restrict__ Wke, short* __restrict__ Wve) {
    const int mode = blockIdx.y;
    const float* W = (mode == 0) ? Wq : (mode == 1) ? Wk : Wv;
    const float* A = (mode == 0) ? Aq : Av;
    const float* Bm = (mode == 0) ? Bq : Bv;
    short* outp = (mode == 0) ? Wqe : (mode == 1) ? Wke : Wve;
    int idx = blockIdx.x * 256 + threadIdx.x;        // 1M elems
    int n = idx >> 10, k = idx & 1023;
    float v = W[idx];
    if (mode != 1) {
        float s = 0.f;
#pragma unroll
        for (int r = 0; r < 8; ++r) s += Bm[n * 8 + r] * A[r * 1024 + k];
        v += 2.0f * s;
    }
    outp[idx] = f2bf(v);
}

// ---- projection GEMM v3: 64M x 128N tile, double-buffered overlap pipeline ----
// Stage(t+1) issued BEFORE compute(t); one __syncthreads per K-step (drain lands
// after a full MFMA phase -> fetch latency hidden under compute). 48KB LDS, 3 blk/CU.
// z = 0: Q (scale 0.125*log2e, [b][h][t][d]); z=1: K; z=2: V^T (half-swapped).
__global__ __launch_bounds__(256, 3) void proj_gemm(
        const short* __restrict__ Xbf,
        const short* __restrict__ Wq, const short* __restrict__ Wk, const short* __restrict__ Wv,
        const float* __restrict__ bq, const float* __restrict__ bk, const float* __restrict__ bv,
        short* __restrict__ Qb, short* __restrict__ Kb, short* __restrict__ Vtb) {
    __shared__ __align__(16) char As[2][64 * 128];   // X tiles (8KB each), swizzled
    __shared__ __align__(16) char Bs[2][128 * 128];  // W tiles (16KB each), swizzled

    const int mode = blockIdx.z;
    const short* Wbf = (mode == 0) ? Wq : (mode == 1) ? Wk : Wv;
    const float* bias = (mode == 0) ? bq : (mode == 1) ? bk : bv;
    short* outp = (mode == 0) ? Qb : (mode == 1) ? Kb : Vtb;
    const float scale = (mode == 0) ? 0.18033688f : 1.0f;  // HD^-0.5 * log2(e)

    const int tid = threadIdx.x;
    const int wave = tid >> 6, lane = tid & 63;
    const int l15 = lane & 15, l4 = lane >> 4;
    // XCD rectangle swizzle (bijective): XCD = bx owns 2 W-panels x 32 X-panels
    const int bx = blockIdx.x, by = blockIdx.y;
    const int wx = 2 * (bx & 3) + (by & 1);          // W panel 0..7
    const int wy = (bx >> 2) * 32 + (by >> 1);       // X panel 0..63
    const int m0 = wy * 64, n0 = wx * 128;
    const int wm = (wave >> 1) * 32, wn = (wave & 1) * 64;

    const int lrow8 = lane >> 3;                     // 0..7
    const int lchunk = lane & 7;                     // 16B chunk
    const int srcoff = (lchunk ^ lrow8) * 8;         // shorts (pre-swizzled source)

#define PROJ_STAGE(BUF, K0) do {                                                     \
    _Pragma("unroll")                                                                \
    for (int i = 0; i < 2; ++i)                                                      \
        gl_lds16(Xbf + (m0 + wave * 16 + i * 8 + lrow8) * 1024 + (K0) + srcoff,      \
                 As[BUF] + wave * 2048 + i * 1024);                                  \
    _Pragma("unroll")                                                                \
    for (int i = 0; i < 4; ++i)                                                      \
        gl_lds16(Wbf + (n0 + wave * 32 + i * 8 + lrow8) * 1024 + (K0) + srcoff,      \
                 Bs[BUF] + wave * 4096 + i * 1024);                                  \
} while (0)

#define PROJ_FRAGS(BUF, KK)                                                          \
    const int colb = (KK) * 64 + l4 * 16;                                            \
    bf16x8 wf[4], xf[2];                                                             \
    _Pragma("unroll")                                                                \
    for (int w = 0; w < 4; ++w) {                                                    \
        int r = wn + w * 16 + l15;                                                   \
        wf[w] = *reinterpret_cast<const bf16x8*>(Bs[BUF] + ((r * 128 + colb) ^ ((r & 7) << 4))); \
    }                                                                                \
    _Pragma("unroll")                                                                \
    for (int x = 0; x < 2; ++x) {                                                    \
        int r = wm + x * 16 + l15;                                                   \
        xf[x] = *reinterpret_cast<const bf16x8*>(As[BUF] + ((r * 128 + colb) ^ ((r & 7) << 4))); \
    }

#define PROJ_MFMA_T(BUF) do {                                                        \
    _Pragma("unroll")                                                                \
    for (int kk = 0; kk < 2; ++kk) {                                                 \
        PROJ_FRAGS(BUF, kk);                                                         \
        _Pragma("unroll")                                                            \
        for (int w = 0; w < 4; ++w)                                                  \
            _Pragma("unroll")                                                        \
            for (int x = 0; x < 2; ++x)                                              \
                acc[w][x] = __builtin_amdgcn_mfma_f32_16x16x32_bf16(wf[w], xf[x], acc[w][x], 0, 0, 0); \
    }                                                                                \
} while (0)

#define PROJ_MFMA_N(BUF) do {                                                        \
    _Pragma("unroll")                                                                \
    for (int kk = 0; kk < 2; ++kk) {                                                 \
        PROJ_FRAGS(BUF, kk);                                                         \
        _Pragma("unroll")                                                            \
        for (int x = 0; x < 2; ++x)                                                  \
            _Pragma("unroll")                                                        \
            for (int w = 0; w < 4; ++w)                                              \
                acc[x][w] = __builtin_amdgcn_mfma_f32_16x16x32_bf16(xf[x], wf[w], acc[x][w], 0, 0, 0); \
    }                                                                                \
} while (0)

    if (mode != 2) {
        // C^T orientation: C rows = features, cols = tokens
        f32x4 acc[4][2] = {};
        PROJ_STAGE(0, 0);
        __syncthreads();                             // prologue drain
        for (int t = 0; t < 16; t += 2) {
            PROJ_STAGE(1, (t + 1) * 64);             // overlap: issue before compute
            PROJ_MFMA_T(0);
            __syncthreads();                         // drains stage(t+1); reads of buf0 done
            if (t + 2 < 16) PROJ_STAGE(0, (t + 2) * 64);
            PROJ_MFMA_T(1);
            __syncthreads();
        }
#pragma unroll
        for (int w = 0; w < 4; ++w) {
            int gnb = n0 + wn + w * 16 + l4 * 4;     // 4 consecutive features
            int hh = gnb >> 6, d = gnb & 63;
            float4 bv4 = *reinterpret_cast<const float4*>(bias + gnb);
#pragma unroll
            for (int x = 0; x < 2; ++x) {
                int gm = m0 + wm + x * 16 + l15;
                int bb = gm >> 11, t = gm & 2047;
                short4v o;
                o[0] = f2bf((acc[w][x][0] + bv4.x) * scale);
                o[1] = f2bf((acc[w][x][1] + bv4.y) * scale);
                o[2] = f2bf((acc[w][x][2] + bv4.z) * scale);
                o[3] = f2bf((acc[w][x][3] + bv4.w) * scale);
                *reinterpret_cast<short4v*>(outp + ((bb * 16 + hh) * 2048 + t) * 64 + d) = o;
            }
        }
    } else {
        // C orientation: rows = tokens, cols = features; V^T [d][t] with half-swap
        f32x4 acc[2][4] = {};
        PROJ_STAGE(0, 0);
        __syncthreads();
        for (int t = 0; t < 16; t += 2) {
            PROJ_STAGE(1, (t + 1) * 64);
            PROJ_MFMA_N(0);
            __syncthreads();
            if (t + 2 < 16) PROJ_STAGE(0, (t + 2) * 64);
            PROJ_MFMA_N(1);
            __syncthreads();
        }
#pragma unroll
        for (int x = 0; x < 2; ++x) {
            int gmb = m0 + wm + x * 16 + l4 * 4;     // 4 consecutive tokens
            int bb = gmb >> 11, t = gmb & 2047;
#pragma unroll
            for (int w = 0; w < 4; ++w) {
                int gn = n0 + wn + w * 16 + l15;
                int hh = gn >> 6, d = gn & 63;
                int tx = ((gn >> 3) & 1) << 2;       // half-swap for attn V read
                float bvs = bias[gn];
                short4v o;
                o[0] = f2bf(acc[x][w][0] + bvs);
                o[1] = f2bf(acc[x][w][1] + bvs);
                o[2] = f2bf(acc[x][w][2] + bvs);
                o[3] = f2bf(acc[x][w][3] + bvs);
                *reinterpret_cast<short4v*>(outp + ((bb * 16 + hh) * 64 + d) * 2048 + (t ^ tx)) = o;
            }
        }
    }
}

// ---- flash attention v12: v11 + unroll-by-4 stream loop (static LDS bases) ----

#define STAGE(BUF, T) do {                                                           \
    const int _kv = (T) << 5;                                                        \
    gl_lds16(Kp + (_kv + krow) * 64 + kswz, MEM + (BUF) * 4096 + wv * 1024);         \
    gl_lds16(Vp + lane * 2048 + _kv + wv * 8, MEM + 16384 + (BUF) * 4096 + wv * 1024);\
} while (0)

#define SLICEJOB(QF0, QF1, OO, M, L, QBASE) do {                                     \
    f32x4 ss = {};                                                                   \
    ss = __builtin_amdgcn_mfma_f32_16x16x32_bf16(kf0, QF0, ss, 0, 0, 0);             \
    ss = __builtin_amdgcn_mfma_f32_16x16x32_bf16(kf1, QF1, ss, 0, 0, 0);             \
    float pr[4];                                                                     \
    if (kvs + 15 > (QBASE)) {                                                        \
        _Pragma("unroll")                                                            \
        for (int r = 0; r < 4; ++r) {                                                \
            float v = ss[r] + mv[r];                                                 \
            if (kvs + l4*4 + r > (QBASE) + l15) v = -1e30f;                          \
            pr[r] = v;                                                               \
        }                                                                            \
    } else {                                                                         \
        _Pragma("unroll")                                                            \
        for (int r = 0; r < 4; ++r) pr[r] = ss[r] + mv[r];                           \
    }                                                                                \
    float tl = fmaxf(fmaxf(pr[0], pr[1]), fmaxf(pr[2], pr[3]));                      \
    if (!__all(tl - (M) <= 11.5415603f)) {                                           \
        float tm = tl;                                                               \
        tm = fmaxf(tm, __shfl_xor(tm, 16));                                          \
        tm = fmaxf(tm, __shfl_xor(tm, 32));                                          \
        float mn = fmaxf((M), tm);                                                   \
        float al = ex2((M) - mn);                                                    \
        M = mn; L *= al;                                                             \
        _Pragma("unroll")                                                            \
        for (int dt = 0; dt < 4; ++dt)                                               \
            _Pragma("unroll")                                                        \
            for (int r = 0; r < 4; ++r) OO[dt][r] *= al;                             \
    }                                                                                \
    _Pragma("unroll")                                                                \
    for (int r = 0; r < 4; ++r) pr[r] = ex2(pr[r] - (M));                            \
    L += (pr[0] + pr[1]) + (pr[2] + pr[3]);                                          \
    short4v pa;                                                                      \
    _Pragma("unroll")                                                                \
    for (int r = 0; r < 4; ++r) pa[r] = f2bf(pr[r]);                                 \
    _Pragma("unroll")                                                                \
    for (int dt = 0; dt < 4; ++dt)                                                   \
        OO[dt] = __builtin_amdgcn_mfma_f32_16x16x16bf16_1k(vf[dt], pa, OO[dt], 0, 0, 0); \
} while (0)

#define AITER(BUF, T) do {                                                           \
    if ((T) + 2 < NT) {                                                              \
        STAGE((((BUF) + 2) & 3), (T) + 2);                                           \
        asm volatile("s_waitcnt vmcnt(4)" ::: "memory");                             \
    } else if ((T) + 1 < NT) {                                                       \
        asm volatile("s_waitcnt vmcnt(2)" ::: "memory");                             \
    } else {                                                                         \
        asm volatile("s_waitcnt vmcnt(0)" ::: "memory");                             \
    }                                                                                \
    asm volatile("s_barrier" ::: "memory");                                          \
    if ((T) < nkA) {                                                                 \
        const char* Kcur = MEM + (BUF) * 4096;                                       \
        const char* Vcur = MEM + 16384 + (BUF) * 4096;                               \
        bf16x8 kf0 = *reinterpret_cast<const bf16x8*>(Kcur + kb0);                   \
        bf16x8 kf1 = *reinterpret_cast<const bf16x8*>(Kcur + (kb0 ^ 64));            \
        short4v vf[4];                                                               \
        _Pragma("unroll")                                                            \
        for (int dt = 0; dt < 4; ++dt)                                               \
            vf[dt] = *reinterpret_cast<const short4v*>(Vcur + vb0 + dt * 256);       \
        const int kvs = ((T) << 5) + 16 * s;                                         \
        float4 mv = *reinterpret_cast<const float4*>(mlds + kvs + l4 * 4);           \
        SLICEJOB(qfA0, qfA1, OA, MA, LA, qbaseA);                                    \
        if ((T) < nkB) SLICEJOB(qfB0, qfB1, OB, MB, LB, qbaseB);                     \
    }                                                                                \
} while (0)

// LDS (bytes): K 4-buf [4][4096] @0 | V 4-buf [4][4096] @16384 | mask 8192 @32768 = 40960
// merge regions reuse @0 after the stream loop (20480 B, over dead K/V buffers)
__global__ __launch_bounds__(256, 4) void attn(
        const short* __restrict__ Qb, const short* __restrict__ Kb,
        const short* __restrict__ Vt, const float* __restrict__ amask,
        float* __restrict__ outp) {
    __shared__ __align__(16) char MEM[40960];

    const int tid = threadIdx.x, wv = tid >> 6, lane = tid & 63;
    const int l15 = lane & 15, l4 = lane >> 4;
    // XCD-chunked + bit-mixed j: robust CU-level balance under round-robin fill
    const int xcd = blockIdx.x & 7;
    const int k   = blockIdx.x >> 3;                 // 0..127 within XCD
    const int j   = ((k >> 5) << 3) | ((k & 3) << 1) | ((k >> 4) & 1);  // 0..31
    const int bh  = xcd * 4 + ((k >> 2) & 3);        // 4 bh per XCD (L2 locality)
    const int p  = wv & 1;                           // pair in block
    const int s  = wv >> 1;                          // key-slice
    const int i  = 2 * j + p;                        // pair index 0..63
    const int b = bh >> 4, h = bh & 15;

    const short* Qp = Qb + bh * TT * HDD;
    const short* Kp = Kb + bh * TT * HDD;
    const short* Vp = Vt + bh * HDD * TT;
    const float* mp = amask + b * TT;
    float* mlds = (float*)(MEM + 32768);

    const int qbaseA = (127 - i) << 4;
    const int qbaseB = i << 4;
    const int nkA = ((qbaseA + 15 - 16 * s) >> 5) + 1;   // slice-aware causal bounds
    const int nkB = ((qbaseB + 15 - 16 * s) >> 5) + 1;   // (0 when slice fully masked)
    const int NT = ((127 - 2 * j) * 16 + 47) >> 5;       // block stream extent (>= 33)

    // staging lane geometry: K rows [wv*8,+8) pre-swizzled; V chunk wv, d=lane
    const int krow = wv * 8 + (lane >> 3);
    const int kswz = ((lane & 7) ^ (lane >> 3)) * 8;     // shorts

    // LDS read offsets (bytes)
    const int kb0 = (16 * s + l15) * 128 + ((l4 ^ (l15 & 7)) << 4);
    const int vb0 = (2 * s + (l4 >> 1)) * 1024 + l15 * 16 + (((l4 & 1) ^ (l15 >> 3)) << 3);

    // prologue: mask -> LDS (whole row for this b), scaled to log2 domain
    {
        int mi8 = tid * 8;
        float4 a = *reinterpret_cast<const float4*>(mp + mi8);
        float4 c = *reinterpret_cast<const float4*>(mp + mi8 + 4);
        a.x *= 1.44269504f; a.y *= 1.44269504f; a.z *= 1.44269504f; a.w *= 1.44269504f;
        c.x *= 1.44269504f; c.y *= 1.44269504f; c.z *= 1.44269504f; c.w *= 1.44269504f;
        *reinterpret_cast<float4*>(mlds + mi8) = a;
        *reinterpret_cast<float4*>(mlds + mi8 + 4) = c;
    }

    bf16x8 qfA0 = *reinterpret_cast<const bf16x8*>(Qp + (qbaseA + l15) * 64 + l4 * 8);
    bf16x8 qfA1 = *reinterpret_cast<const bf16x8*>(Qp + (qbaseA + l15) * 64 + 32 + l4 * 8);
    bf16x8 qfB0 = *reinterpret_cast<const bf16x8*>(Qp + (qbaseB + l15) * 64 + l4 * 8);
    bf16x8 qfB1 = *reinterpret_cast<const bf16x8*>(Qp + (qbaseB + l15) * 64 + 32 + l4 * 8);

    f32x4 OA[4] = {}, OB[4] = {};
    float MA = -1e30f, LA = 0.f, MB = -1e30f, LB = 0.f;

    STAGE(0, 0);                                     // tiles 0,1 in flight
    STAGE(1, 1);                                     // (NT >= 33, both exist)
    asm volatile("s_waitcnt lgkmcnt(0)" ::: "memory");   // mask writes retired

    int t = 0;
    for (; t + 4 <= NT; t += 4) {                    // unrolled: static buffer bases
        AITER(0, t);
        AITER(1, t + 1);
        AITER(2, t + 2);
        AITER(3, t + 3);
    }
    for (; t < NT; ++t) AITER((t & 3), t);           // tail (0..3 iters)

    asm volatile("s_barrier" ::: "memory");          // loop reads done before merge reuse

    // reduce l across l4 groups (per slice)
    LA += __shfl_xor(LA, 16); LA += __shfl_xor(LA, 32);
    LB += __shfl_xor(LB, 16); LB += __shfl_xor(LB, 32);

    // disjoint-key merge: slice-1 posts, slice-0 merges + writes
    float* mg = (float*)MEM + p * 2560 + lane * 40;  // 160B/lane, 16B-aligned chunks
    if (s) {
#pragma unroll
        for (int dt = 0; dt < 4; ++dt) *reinterpret_cast<f32x4*>(mg + dt * 4) = OA[dt];
        mg[16] = MA; mg[17] = LA;
#pragma unroll
        for (int dt = 0; dt < 4; ++dt) *reinterpret_cast<f32x4*>(mg + 20 + dt * 4) = OB[dt];
        mg[36] = MB; mg[37] = LB;
    }
    __syncthreads();
    if (!s) {
        {
            float m1 = mg[16], l1 = mg[17];
            float ms = fmaxf(MA, m1);
            float e0 = ex2(MA - ms), e1 = ex2(m1 - ms);
            float inv = 1.0f / (LA * e0 + l1 * e1);
            int tA = qbaseA + l15;
#pragma unroll
            for (int dt = 0; dt < 4; ++dt) {
                f32x4 o1 = *reinterpret_cast<const f32x4*>(mg + dt * 4);
                float4 o;
                o.x = (OA[dt][0] * e0 + o1[0] * e1) * inv;
                o.y = (OA[dt][1] * e0 + o1[1] * e1) * inv;
                o.z = (OA[dt][2] * e0 + o1[2] * e1) * inv;
                o.w = (OA[dt][3] * e0 + o1[3] * e1) * inv;
                *reinterpret_cast<float4*>(outp + (b * 2048 + tA) * 1024 + h * 64 + dt * 16 + l4 * 4) = o;
            }
        }
        {
            float m1 = mg[36], l1 = mg[37];
            float ms = fmaxf(MB, m1);
            float e0 = ex2(MB - ms), e1 = ex2(m1 - ms);
            float inv = 1.0f / (LB * e0 + l1 * e1);
            int tB = qbaseB + l15;
#pragma unroll
            for (int dt = 0; dt < 4; ++dt) {
                f32x4 o1 = *reinterpret_cast<const f32x4*>(mg + 20 + dt * 4);
                float4 o;
                o.x = (OB[dt][0] * e0 + o1[0] * e1) * inv;
                o.y = (OB[dt][1] * e0 + o1[1] * e1) * inv;
                o.z = (OB[dt][2] * e0 + o1[2] * e1) * inv;
                o.w = (OB[dt][3] * e0 + o1[3] * e1) * inv;
                *reinterpret_cast<float4*>(outp + (b * 2048 + tB) * 1024 + h * 64 + dt * 16 + l4 * 4) = o;
            }
        }
    }
}

extern "C" void kernel_launch(void* const* d_in, const int* in_sizes, int n_in,
                              void* d_out, int out_size, void* d_ws, size_t ws_size,
                              hipStream_t stream) {
    const float* hidden = (const float*)d_in[0];
    const float* amask  = (const float*)d_in[1];
    const float* Wq = (const float*)d_in[2];
    const float* bq = (const float*)d_in[3];
    const float* Aq = (const float*)d_in[4];
    const float* Bq = (const float*)d_in[5];
    const float* Wk = (const float*)d_in[6];
    const float* bk = (const float*)d_in[7];
    const float* Wv = (const float*)d_in[8];
    const float* bv = (const float*)d_in[9];
    const float* Av = (const float*)d_in[10];
    const float* Bv = (const float*)d_in[11];
    float* outp = (float*)d_out;

    char* ws = (char*)d_ws;
    short* Xbf = (short*)(ws);                 // 8 MB  [4096][1024] bf16
    short* Wqe = (short*)(ws + (8 << 20));     // 2 MB
    short* Wke = (short*)(ws + (10 << 20));    // 2 MB
    short* Wve = (short*)(ws + (12 << 20));    // 2 MB
    short* Qb  = (short*)(ws + (14 << 20));    // 8 MB  [b][h][t][d] (pre-scaled by 0.125*log2e)
    short* Kb  = (short*)(ws + (22 << 20));    // 8 MB  [b][h][t][d]
    short* Vtb = (short*)(ws + (30 << 20));    // 8 MB  [b][h][d][t] (half-swapped)

    cvt_hidden<<<4096, 256, 0, stream>>>(hidden, Xbf);
    prep_w<<<dim3(4096, 3), 256, 0, stream>>>(Wq, Aq, Bq, Wk, Wv, Av, Bv, Wqe, Wke, Wve);
    proj_gemm<<<dim3(8, 64, 3), 256, 0, stream>>>(Xbf, Wqe, Wke, Wve, bq, bk, bv, Qb, Kb, Vtb);
    attn<<<1024, 256, 0, stream>>>(Qb, Kb, Vtb, amask, outp);
}